// Round 11
// baseline (739.054 us; speedup 1.0000x reference)
//
#include <hip/hip_runtime.h>
#include <cstdint>
#include <cstddef>

#define NNODE 4096
#define FIND  2048
#define HD_   256
#define NC_   10
#define THRESH_ 0.05f
#define LOG2E_ 1.4426950408889634f

typedef unsigned long long u64;
typedef __attribute__((ext_vector_type(8))) short bf16x8;
typedef __attribute__((ext_vector_type(4))) float f32x4;

// ---------- bf16 split helpers ----------
__device__ inline unsigned short f2bf_rne(float f){
  unsigned u = __builtin_bit_cast(unsigned, f);
  unsigned r = u + 0x7FFFu + ((u >> 16) & 1u);
  return (unsigned short)(r >> 16);
}
__device__ inline float bf2f(unsigned short h){
  unsigned u = ((unsigned)h) << 16;
  return __builtin_bit_cast(float, u);
}
__device__ __forceinline__ float fexp2(float x){ return __builtin_amdgcn_exp2f(x); }

// order-preserving fp32 <-> uint encoding for atomicMax
__device__ inline unsigned fenc(float f){
  unsigned u = __builtin_bit_cast(unsigned, f);
  return (u & 0x80000000u) ? ~u : (u | 0x80000000u);
}
__device__ inline float fdec(unsigned k){
  unsigned u = (k & 0x80000000u) ? (k & 0x7FFFFFFFu) : ~k;
  return __builtin_bit_cast(float, u);
}

// async global->LDS, 16B per lane; lds dest is wave-uniform base (+lane*16 by HW)
__device__ __forceinline__ void gld16(const void* g, void* l){
  __builtin_amdgcn_global_load_lds(
      (const __attribute__((address_space(1))) unsigned int*)g,
      (__attribute__((address_space(3))) unsigned int*)l, 16, 0, 0);
}

// ---------- row normalize -> hi/lo bf16 ----------
__global__ void rownorm_bf(const float* __restrict__ x,
                           unsigned short* __restrict__ oh, unsigned short* __restrict__ ol){
  int row = blockIdx.x; int t = threadIdx.x;
  const float4* xr = reinterpret_cast<const float4*>(x + (size_t)row*FIND);
  float s = 0.f;
  #pragma unroll
  for (int i = 0; i < FIND/4/256; ++i){
    float4 v = xr[t + i*256];
    s += v.x*v.x + v.y*v.y + v.z*v.z + v.w*v.w;
  }
  #pragma unroll
  for (int o = 32; o > 0; o >>= 1) s += __shfl_down(s, o);
  __shared__ float red[4];
  __shared__ float invn;
  if ((t & 63) == 0) red[t >> 6] = s;
  __syncthreads();
  if (t == 0) invn = rsqrtf(red[0] + red[1] + red[2] + red[3]);
  __syncthreads();
  float inv = invn;
  #pragma unroll
  for (int i = 0; i < FIND/4/256; ++i){
    float4 v = xr[t + i*256];
    float a[4] = {v.x*inv, v.y*inv, v.z*inv, v.w*inv};
    ushort4 hv, lv;
    unsigned short* hp = &hv.x; unsigned short* lp = &lv.x;
    #pragma unroll
    for (int j = 0; j < 4; ++j){
      unsigned short h = f2bf_rne(a[j]);
      hp[j] = h; lp[j] = f2bf_rne(a[j] - bf2f(h));
    }
    size_t off = (size_t)row*FIND + (t + i*256)*4;
    *reinterpret_cast<ushort4*>(oh + off) = hv;
    *reinterpret_cast<ushort4*>(ol + off) = lv;
  }
}

// ---------- fp32 -> bf16 hi only (vectorized) ----------
__global__ void f2bf1_k(const float* __restrict__ in, unsigned short* __restrict__ oh, int n4){
  int idx = blockIdx.x*256 + threadIdx.x;
  if (idx >= n4) return;
  float4 v = reinterpret_cast<const float4*>(in)[idx];
  ushort4 hv;
  hv.x = f2bf_rne(v.x); hv.y = f2bf_rne(v.y);
  hv.z = f2bf_rne(v.z); hv.w = f2bf_rne(v.w);
  reinterpret_cast<ushort4*>(oh)[idx] = hv;
}

// ---------- weight prep: R [K, H*F] -> outT [F, K] (sum over H), tiled LDS transpose ----------
template<int H>
__global__ void foldT_k(const float* __restrict__ R, unsigned short* __restrict__ oh,
                        unsigned short* __restrict__ ol, int K, int F, int ktiles){
  int bid = blockIdx.x;
  int f0 = (bid / ktiles) * 64, k0 = (bid % ktiles) * 64;
  __shared__ float tile[64][65];
  int t = threadIdx.x;
  {
    int tf = t & 63, tk4 = t >> 6;
    #pragma unroll
    for (int m = 0; m < 16; ++m){
      int kl = tk4 + m*4;
      float s = 0.f;
      #pragma unroll
      for (int h = 0; h < H; ++h)
        s += R[(size_t)(k0 + kl)*(H*F) + h*F + f0 + tf];
      tile[kl][tf] = s;
    }
  }
  __syncthreads();
  {
    int tk = t & 63, tf4 = t >> 6;
    #pragma unroll
    for (int m = 0; m < 16; ++m){
      int fl = tf4 + m*4;
      float s = tile[tk][fl];
      unsigned short hv = f2bf_rne(s);
      size_t o = (size_t)(f0 + fl)*K + k0 + tk;
      oh[o] = hv;
      ol[o] = f2bf_rne(s - bf2f(hv));
    }
  }
}

__global__ void bfold_k(const float* __restrict__ b, float* __restrict__ out, int H, int F){
  int f = threadIdx.x;
  if (f < F){
    float s = 0.f;
    for (int h = 0; h < H; ++h) s += b[h*F + f];
    out[f] = s;
  }
}

// ---------- attention-vector fold: val[k][h]=sum_f W[k][h*256+f]*al[h][f]; val[k][H+h]=...ar ----------
// one wave per (k,h); 4 waves/block. Optionally inits the 12-word MELG atomic buffer.
template<int H, bool INIT>
__global__ void valprep_k(const float* __restrict__ W, const float* __restrict__ al,
                          const float* __restrict__ ar, float* __restrict__ val,
                          unsigned* __restrict__ melg){
  int t = threadIdx.x, lane = t & 63, w = t >> 6;
  if (INIT && blockIdx.x == 0 && t < 12) melg[t] = 0u;
  int task = blockIdx.x*4 + w;
  int k = task / H, h = task % H;
  float4 wv = *reinterpret_cast<const float4*>(W + (size_t)k*(H*256) + h*256 + lane*4);
  float4 av = *reinterpret_cast<const float4*>(al + h*256 + lane*4);
  float4 rv = *reinterpret_cast<const float4*>(ar + h*256 + lane*4);
  float e = wv.x*av.x + wv.y*av.y + wv.z*av.z + wv.w*av.w;
  float r = wv.x*rv.x + wv.y*rv.y + wv.z*rv.z + wv.w*rv.w;
  #pragma unroll
  for (int o = 32; o > 0; o >>= 1){ e += __shfl_down(e, o); r += __shfl_down(r, o); }
  if (lane == 0){
    val[(size_t)k*2*H + h] = e;
    val[(size_t)k*2*H + H + h] = r;
  }
}

// ---------- el0/er0 = x @ val0 (x fp32, val0 [2048][8]); atomicMax MELG0 ----------
__global__ void el0gemv_k(const float* __restrict__ x, const float* __restrict__ val0,
                          float* __restrict__ el2, float* __restrict__ er2,
                          unsigned* __restrict__ melg0){
  int n = blockIdx.x, t = threadIdx.x;
  float acc[8] = {};
  #pragma unroll
  for (int i = 0; i < 8; ++i){
    int k = i*256 + t;
    float xv = x[(size_t)n*FIND + k];
    float4 v0 = *reinterpret_cast<const float4*>(val0 + (size_t)k*8);
    float4 v1 = *reinterpret_cast<const float4*>(val0 + (size_t)k*8 + 4);
    acc[0] += xv*v0.x; acc[1] += xv*v0.y; acc[2] += xv*v0.z; acc[3] += xv*v0.w;
    acc[4] += xv*v1.x; acc[5] += xv*v1.y; acc[6] += xv*v1.z; acc[7] += xv*v1.w;
  }
  __shared__ float red[4][8];
  #pragma unroll
  for (int j = 0; j < 8; ++j){
    float v = acc[j];
    #pragma unroll
    for (int o = 32; o > 0; o >>= 1) v += __shfl_down(v, o);
    if ((t & 63) == 0) red[t >> 6][j] = v;
  }
  __syncthreads();
  if (t < 4){
    int h = t;
    float el = (red[0][h] + red[1][h] + red[2][h] + red[3][h]) * LOG2E_;
    float er = (red[0][4+h] + red[1][4+h] + red[2][4+h] + red[3][4+h]) * LOG2E_;
    el2[(size_t)n*4 + h] = el;
    er2[(size_t)n*4 + h] = er;
    atomicMax(&melg0[h], fenc(el));
  }
}

// ---------- MEGA GEMM: role-interleaved per XCD (load-balanced) ----------
// 1104 blocks = 8 XCDs x 138. Per XCD: 66 Gram(3-term) + 40 GAT0(2-term) + 32 MLP(2-term).
__global__ void mega_gemm(const unsigned short* __restrict__ XNh, const unsigned short* __restrict__ XNl,
                          const unsigned short* __restrict__ Xh,
                          const unsigned short* __restrict__ W0h, const unsigned short* __restrict__ W0l,
                          const unsigned short* __restrict__ WLh, const unsigned short* __restrict__ WLl,
                          float* __restrict__ FT, unsigned short* __restrict__ FTB,
                          float* __restrict__ Z1, u64* __restrict__ Mk){
  __shared__ unsigned short smem[4*128*32];
  unsigned short* sAh = smem;
  unsigned short* sAl = smem + 4096;
  unsigned short* sBh = smem + 8192;
  unsigned short* sBl = smem + 12288;
  const int t = threadIdx.x, lane = t & 63, w = t >> 6;
  const int wr = w >> 1, wc = w & 1, l15 = lane & 15, lg = lane >> 4;

  const int bid = blockIdx.x;
  const int xcd = bid & 7, idx = bid >> 3;   // blocks round-robin to XCDs by bid&7

  int role, brow, bcol;
  const unsigned short *Ah, *Al = nullptr, *Bh, *Bl;
  float* C = nullptr; int ldc = 0; size_t ldb;
  if (idx < 66){
    role = 0;
    int g = xcd*66 + idx;                    // 0..527 upper-tri
    int rem = g, i = 0;
    while (rem >= 32 - i){ rem -= 32 - i; ++i; }
    brow = i; bcol = i + rem;
    Ah = XNh; Al = XNl; Bh = XNh; Bl = XNl; ldb = FIND;
  } else if (idx < 106){
    role = 1;
    int l = xcd*40 + (idx - 66);             // 0..319
    brow = l / 10; bcol = l % 10;
    Ah = Xh; Bh = W0h; Bl = W0l; ldb = FIND;
    C = FT; ldc = 1280;
  } else {
    role = 2;
    int l = xcd*32 + (idx - 106);            // 0..255
    brow = l >> 3; bcol = l & 7;
    Ah = Xh; Bh = WLh; Bl = WLl; ldb = 2304;
    C = Z1; ldc = 1024;
  }
  const bool three = (role == 0);
  const int row0 = brow*128, col0 = bcol*128;

  const int c0 = 2*w, c1 = 2*w + 1;
  const int rsub = lane >> 2, piece = lane & 3;
  const size_t ld2a = (size_t)FIND*2, ld2b = ldb*2;
  const size_t a0 = (size_t)(row0 + 16*c0 + rsub)*ld2a + piece*16;
  const size_t a1 = (size_t)(row0 + 16*c1 + rsub)*ld2a + piece*16;
  const size_t b0 = (size_t)(col0 + 16*c0 + rsub)*ld2b + piece*16;
  const size_t b1 = (size_t)(col0 + 16*c1 + rsub)*ld2b + piece*16;
  const char* pA0h = (const char*)Ah + a0;  const char* pA1h = (const char*)Ah + a1;
  const char* pA0l = three ? (const char*)Al + a0 : nullptr;
  const char* pA1l = three ? (const char*)Al + a1 : nullptr;
  const char* pB0h = (const char*)Bh + b0;  const char* pB1h = (const char*)Bh + b1;
  const char* pB0l = (const char*)Bl + b0;  const char* pB1l = (const char*)Bl + b1;
  char* lA0h = (char*)sAh + c0*1024;  char* lA1h = (char*)sAh + c1*1024;
  char* lA0l = (char*)sAl + c0*1024;  char* lA1l = (char*)sAl + c1*1024;
  char* lB0h = (char*)sBh + c0*1024;  char* lB1h = (char*)sBh + c1*1024;
  char* lB0l = (char*)sBl + c0*1024;  char* lB1l = (char*)sBl + c1*1024;

  f32x4 acc[4][4] = {};
  for (int kt = 0; kt < 64; ++kt){
    __syncthreads();
    gld16(pA0h, lA0h); gld16(pA1h, lA1h);
    if (three){
      gld16(pA0l, lA0l); gld16(pA1l, lA1l);
      pA0l += 64; pA1l += 64;
    }
    gld16(pB0h, lB0h); gld16(pB1h, lB1h);
    gld16(pB0l, lB0l); gld16(pB1l, lB1l);
    pA0h += 64; pA1h += 64;
    pB0h += 64; pB1h += 64; pB0l += 64; pB1l += 64;
    __syncthreads();
    bf16x8 fb_h[4], fb_l[4];
    #pragma unroll
    for (int j = 0; j < 4; ++j){
      int bo = (wc*64 + j*16 + l15)*32 + lg*8;
      fb_h[j] = *reinterpret_cast<const bf16x8*>(sBh + bo);
      fb_l[j] = *reinterpret_cast<const bf16x8*>(sBl + bo);
    }
    #pragma unroll
    for (int i = 0; i < 4; ++i){
      int ao = (wr*64 + i*16 + l15)*32 + lg*8;
      bf16x8 fah = *reinterpret_cast<const bf16x8*>(sAh + ao);
      #pragma unroll
      for (int j = 0; j < 4; ++j){
        acc[i][j] = __builtin_amdgcn_mfma_f32_16x16x32_bf16(fah, fb_h[j], acc[i][j], 0, 0, 0);
        acc[i][j] = __builtin_amdgcn_mfma_f32_16x16x32_bf16(fah, fb_l[j], acc[i][j], 0, 0, 0);
      }
      if (three){
        bf16x8 fal = *reinterpret_cast<const bf16x8*>(sAl + ao);
        #pragma unroll
        for (int j = 0; j < 4; ++j)
          acc[i][j] = __builtin_amdgcn_mfma_f32_16x16x32_bf16(fal, fb_h[j], acc[i][j], 0, 0, 0);
      }
    }
  }

  if (role == 0){
    #pragma unroll
    for (int i = 0; i < 4; ++i){
      #pragma unroll
      for (int r = 0; r < 4; ++r){
        u64 bits = 0ull;
        #pragma unroll
        for (int j = 0; j < 4; ++j)
          if (acc[i][j][r] > THRESH_) bits |= 1ull << (j*16 + l15);
        #pragma unroll
        for (int m = 1; m <= 8; m <<= 1) bits |= __shfl_xor(bits, m);
        if (l15 == 0){
          int gr = row0 + wr*64 + i*16 + lg*4 + r;
          Mk[(size_t)gr*64 + (col0 >> 6) + wc] = bits;
        }
      }
    }
    if (row0 != col0){
      #pragma unroll
      for (int j = 0; j < 4; ++j){
        u64 tb = 0ull;
        #pragma unroll
        for (int i = 0; i < 4; ++i)
          #pragma unroll
          for (int r = 0; r < 4; ++r)
            if (acc[i][j][r] > THRESH_) tb |= 1ull << (i*16 + lg*4 + r);
        tb |= __shfl_xor(tb, 16);
        tb |= __shfl_xor(tb, 32);
        if (lg == 0){
          int gc = col0 + wc*64 + j*16 + l15;
          Mk[(size_t)gc*64 + (row0 >> 6) + wr] = tb;
        }
      }
    }
  } else {
    const int f32min = (role == 1) ? 1024 : 0;   // role1: fp32 only residual cols
    #pragma unroll
    for (int i = 0; i < 4; ++i){
      int gr = row0 + wr*64 + i*16 + lg*4;
      #pragma unroll
      for (int j = 0; j < 4; ++j){
        int gc = col0 + wc*64 + j*16 + l15;
        #pragma unroll
        for (int r = 0; r < 4; ++r){
          float v = acc[i][j][r];
          if (role == 1 && gc < 1024) FTB[(size_t)(gr + r)*1280 + gc] = f2bf_rne(v);
          if (gc >= f32min) C[(size_t)(gr + r)*ldc + gc] = v;
        }
      }
    }
  }
}

// ---------- 2-term MFMA NT GEMM (A-hi only; B hi+lo) for short-K layers ----------
// EPI: 0 = store (Cb bf16 where gc<bfmax; C fp32 where gc>=f32min); 3 = C += acc,+bias,leaky
template<int EPI>
__global__ void gemm_bf(const unsigned short* __restrict__ Ah,
                        const unsigned short* __restrict__ Bh, const unsigned short* __restrict__ Bl,
                        float* __restrict__ C, unsigned short* __restrict__ Cb,
                        int K, int lda, int ldb, int ldc, int gridx,
                        const float* __restrict__ bias, float param, int f32min, int bfmax){
  __shared__ unsigned short smem[3*128*32];
  unsigned short* sAh = smem;
  unsigned short* sBh = smem + 4096;
  unsigned short* sBl = smem + 8192;
  const int t = threadIdx.x, lane = t & 63, w = t >> 6;
  const int wr = w >> 1, wc = w & 1, l15 = lane & 15, lg = lane >> 4;

  int nwg = gridDim.x, bid = blockIdx.x;
  int wg = ((nwg & 7) == 0) ? ((bid & 7)*(nwg >> 3) + (bid >> 3)) : bid;
  int brow = wg / gridx, bcol = wg % gridx;
  const int row0 = brow*128, col0 = bcol*128;

  const int c0 = 2*w, c1 = 2*w + 1;
  const int rsub = lane >> 2, piece = lane & 3;
  const size_t ld2a = (size_t)lda*2, ld2b = (size_t)ldb*2;
  const size_t a0 = (size_t)(row0 + 16*c0 + rsub)*ld2a + piece*16;
  const size_t a1 = (size_t)(row0 + 16*c1 + rsub)*ld2a + piece*16;
  const size_t b0 = (size_t)(col0 + 16*c0 + rsub)*ld2b + piece*16;
  const size_t b1 = (size_t)(col0 + 16*c1 + rsub)*ld2b + piece*16;
  const char* pA0h = (const char*)Ah + a0;  const char* pA1h = (const char*)Ah + a1;
  const char* pB0h = (const char*)Bh + b0;  const char* pB1h = (const char*)Bh + b1;
  const char* pB0l = (const char*)Bl + b0;  const char* pB1l = (const char*)Bl + b1;
  char* lA0h = (char*)sAh + c0*1024;  char* lA1h = (char*)sAh + c1*1024;
  char* lB0h = (char*)sBh + c0*1024;  char* lB1h = (char*)sBh + c1*1024;
  char* lB0l = (char*)sBl + c0*1024;  char* lB1l = (char*)sBl + c1*1024;

  f32x4 acc[4][4] = {};
  const int nk = K >> 5;
  for (int kt = 0; kt < nk; ++kt){
    __syncthreads();
    gld16(pA0h, lA0h); gld16(pA1h, lA1h);
    gld16(pB0h, lB0h); gld16(pB1h, lB1h);
    gld16(pB0l, lB0l); gld16(pB1l, lB1l);
    pA0h += 64; pA1h += 64;
    pB0h += 64; pB1h += 64; pB0l += 64; pB1l += 64;
    __syncthreads();
    bf16x8 fb_h[4], fb_l[4];
    #pragma unroll
    for (int j = 0; j < 4; ++j){
      int bo = (wc*64 + j*16 + l15)*32 + lg*8;
      fb_h[j] = *reinterpret_cast<const bf16x8*>(sBh + bo);
      fb_l[j] = *reinterpret_cast<const bf16x8*>(sBl + bo);
    }
    #pragma unroll
    for (int i = 0; i < 4; ++i){
      int ao = (wr*64 + i*16 + l15)*32 + lg*8;
      bf16x8 fah = *reinterpret_cast<const bf16x8*>(sAh + ao);
      #pragma unroll
      for (int j = 0; j < 4; ++j){
        acc[i][j] = __builtin_amdgcn_mfma_f32_16x16x32_bf16(fah, fb_h[j], acc[i][j], 0, 0, 0);
        acc[i][j] = __builtin_amdgcn_mfma_f32_16x16x32_bf16(fah, fb_l[j], acc[i][j], 0, 0, 0);
      }
    }
  }

  #pragma unroll
  for (int i = 0; i < 4; ++i){
    int gr = row0 + wr*64 + i*16 + lg*4;
    #pragma unroll
    for (int j = 0; j < 4; ++j){
      int gc = col0 + wc*64 + j*16 + l15;
      #pragma unroll
      for (int r = 0; r < 4; ++r){
        float v = acc[i][j][r];
        size_t o = (size_t)(gr + r)*ldc + gc;
        if (EPI == 3){
          v += C[o] + bias[gc];
          v = v > 0.f ? v : param*v;
          C[o] = v;
        } else {
          if (gc < bfmax) Cb[o] = f2bf_rne(v);
          if (gc >= f32min) C[o] = v;
        }
      }
    }
  }
}

// ---------- single-pass softmax aggregation (bf16 gather, unmasked-max bound) ----------
// NEXTJ: 8 -> emit next-layer el/er (4 heads) via valw; 2 -> 1 head; 0 -> none.
template<int H, bool RELU, bool OUTF32, int NEXTJ>
__global__ void sagg_k(const unsigned short* __restrict__ FTB, int ldf,
                       const u64* __restrict__ Mk,
                       const float* __restrict__ el2, const float* __restrict__ er2,
                       const unsigned* __restrict__ melg,
                       const float* __restrict__ res, int ldres,
                       const float* __restrict__ bias,
                       float* __restrict__ outf,
                       unsigned short* __restrict__ oh,
                       const float* __restrict__ valw,
                       float* __restrict__ el2n, float* __restrict__ er2n,
                       unsigned* __restrict__ melgn){
  int d = blockIdx.x, t = threadIdx.x;
  const int g = t >> 6, q = t & 63;
  const int h = (H == 4) ? g : 0;
  const int wlo = (H == 1) ? g*16 : 0;
  const int whi = (H == 1) ? wlo + 16 : 64;
  const float er2d = er2[(size_t)d*H + h];
  const float sub = er2d + fdec(melg[h]);
  const float m2 = fmaxf(sub, 0.2f*sub);   // >= all masked scores (leaky monotone)
  const unsigned short* fb = FTB + 4*q + ((H == 4) ? 256*g : 0);
  float4 acc = {0.f, 0.f, 0.f, 0.f};
  float sm = 0.f;
  for (int wdi = wlo; wdi < whi; ++wdi){
    u64 bits = Mk[(size_t)d*64 + wdi];
    while (bits){
      int b = __builtin_ctzll(bits);
      bits &= bits - 1ull;
      int s = wdi*64 + b;
      float sc = er2d + el2[(size_t)s*H + h];
      sc = fmaxf(sc, 0.2f*sc);
      float wt = fexp2(sc - m2);
      sm += wt;
      ushort4 v = *reinterpret_cast<const ushort4*>(fb + (size_t)s*ldf);
      acc.x += wt*bf2f(v.x); acc.y += wt*bf2f(v.y);
      acc.z += wt*bf2f(v.z); acc.w += wt*bf2f(v.w);
    }
  }
  __shared__ float lred[4][256];
  __shared__ float lsm[4];
  if (H == 4){
    float inv = 1.f / sm;    // sm identical across the head's 64 lanes
    acc.x *= inv; acc.y *= inv; acc.z *= inv; acc.w *= inv;
  } else if (q == 0){
    lsm[g] = sm;
  }
  lred[g][q*4+0] = acc.x; lred[g][q*4+1] = acc.y;
  lred[g][q*4+2] = acc.z; lred[g][q*4+3] = acc.w;
  __syncthreads();
  float v = ((lred[0][t] + lred[1][t]) + lred[2][t]) + lred[3][t];
  if (H == 1) v /= (lsm[0] + lsm[1]) + (lsm[2] + lsm[3]);
  v += res[(size_t)d*ldres + t] + bias[t];
  if (RELU) v = fmaxf(v, 0.f);
  if (OUTF32) outf[(size_t)d*HD_ + t] = v;
  oh[(size_t)d*HD_ + t] = f2bf_rne(v);

  // ---- fused next-layer el/er: el_n[d,h] = sum_t v * valw[t][h] ----
  if (NEXTJ > 0){
    float p[NEXTJ > 0 ? NEXTJ : 1];
    if (NEXTJ == 8){
      float4 w0 = *reinterpret_cast<const float4*>(valw + (size_t)t*8);
      float4 w1 = *reinterpret_cast<const float4*>(valw + (size_t)t*8 + 4);
      p[0] = v*w0.x; p[1] = v*w0.y; p[2] = v*w0.z; p[3] = v*w0.w;
      p[4] = v*w1.x; p[5] = v*w1.y; p[6] = v*w1.z; p[7] = v*w1.w;
    } else if (NEXTJ == 2){
      float2 w0 = *reinterpret_cast<const float2*>(valw + (size_t)t*2);
      p[0] = v*w0.x; p[1] = v*w0.y;
    }
    __shared__ float ered[4][NEXTJ > 0 ? NEXTJ : 1];
    #pragma unroll
    for (int j = 0; j < NEXTJ; ++j){
      float pv = p[j];
      #pragma unroll
      for (int o = 32; o > 0; o >>= 1) pv += __shfl_down(pv, o);
      if (q == 0) ered[g][j] = pv;
    }
    __syncthreads();
    const int NH = NEXTJ/2;
    if (t < NH){
      int hh = t;
      float el = (ered[0][hh] + ered[1][hh] + ered[2][hh] + ered[3][hh]) * LOG2E_;
      float er = (ered[0][NH+hh] + ered[1][NH+hh] + ered[2][NH+hh] + ered[3][NH+hh]) * LOG2E_;
      el2n[(size_t)d*NH + hh] = el;
      er2n[(size_t)d*NH + hh] = er;
      atomicMax(&melgn[hh], fenc(el));
    }
  }
}

// ---------- classifier head ----------
__global__ void head_k(const float* __restrict__ A, int K, const float* __restrict__ W,
                       const float* __restrict__ b, float* __restrict__ out){
  int row = blockIdx.x, t = threadIdx.x;
  float p[NC_];
  #pragma unroll
  for (int j = 0; j < NC_; ++j) p[j] = 0.f;
  for (int k = t; k < K; k += 256){
    float a = A[(size_t)row*K + k];
    #pragma unroll
    for (int j = 0; j < NC_; ++j) p[j] += a * W[k*NC_ + j];
  }
  #pragma unroll
  for (int j = 0; j < NC_; ++j){
    #pragma unroll
    for (int o = 32; o > 0; o >>= 1) p[j] += __shfl_down(p[j], o);
  }
  __shared__ float red[4][NC_];
  if ((t & 63) == 0){
    #pragma unroll
    for (int j = 0; j < NC_; ++j) red[t >> 6][j] = p[j];
  }
  __syncthreads();
  if (t < NC_)
    out[(size_t)row*NC_ + t] = red[0][t] + red[1][t] + red[2][t] + red[3][t] + b[t];
}

// ---------- launch ----------
extern "C" void kernel_launch(void* const* d_in, const int* in_sizes, int n_in,
                              void* d_out, int out_size, void* d_ws, size_t ws_size,
                              hipStream_t stream){
  const float* x   = (const float*)d_in[0];
  const float* W0  = (const float*)d_in[1];
  const float* al0 = (const float*)d_in[2];
  const float* ar0 = (const float*)d_in[3];
  const float* b0  = (const float*)d_in[4];
  const float* R0  = (const float*)d_in[5];
  const float* W1  = (const float*)d_in[6];
  const float* al1 = (const float*)d_in[7];
  const float* ar1 = (const float*)d_in[8];
  const float* b1  = (const float*)d_in[9];
  const float* R1  = (const float*)d_in[10];
  const float* W2  = (const float*)d_in[11];
  const float* al2 = (const float*)d_in[12];
  const float* ar2 = (const float*)d_in[13];
  const float* b2  = (const float*)d_in[14];
  const float* Wl1 = (const float*)d_in[15];
  const float* bl1 = (const float*)d_in[16];
  const float* Wc1 = (const float*)d_in[17];
  const float* bc1 = (const float*)d_in[18];
  const float* Wc2 = (const float*)d_in[19];
  const float* bc2 = (const float*)d_in[20];
  (void)in_sizes; (void)n_in; (void)out_size; (void)ws_size;

  char* ws = (char*)d_ws;
  size_t off = 0;
  auto alloc = [&](size_t bytes)->char*{
    char* p = ws + off; off += (bytes + 255) & ~(size_t)255; return p;
  };
  typedef unsigned short us;
  u64* MASK = (u64*)alloc((size_t)NNODE*64*8);
  us* W0h = (us*)alloc((size_t)1280*2048*2);  us* W0l = (us*)alloc((size_t)1280*2048*2);
  us* W1h = (us*)alloc((size_t)1280*256*2);   us* W1l = (us*)alloc((size_t)1280*256*2);
  us* W2h = (us*)alloc((size_t)256*256*2);    us* W2l = (us*)alloc((size_t)256*256*2);
  us* WLh = (us*)alloc((size_t)1024*2304*2);  us* WLl = (us*)alloc((size_t)1024*2304*2);
  float* BF0 = (float*)alloc(256*4);
  float* BF1 = (float*)alloc(256*4);
  float* VAL0 = (float*)alloc((size_t)2048*8*4);
  float* VALW1 = (float*)alloc((size_t)256*8*4);
  float* VALW2 = (float*)alloc((size_t)256*2*4);
  float* EL0 = (float*)alloc((size_t)NNODE*4*4);
  float* ER0 = (float*)alloc((size_t)NNODE*4*4);
  float* EL1 = (float*)alloc((size_t)NNODE*4*4);
  float* ER1 = (float*)alloc((size_t)NNODE*4*4);
  float* EL2c = (float*)alloc((size_t)NNODE*4);
  float* ER2c = (float*)alloc((size_t)NNODE*4);
  unsigned* MELG = (unsigned*)alloc(12*4);   // [0..3]=L0, [4..7]=L1, [8..11]=L2
  us* XNh = (us*)alloc((size_t)NNODE*FIND*2);
  us* XNl = (us*)alloc((size_t)NNODE*FIND*2);
  us* Xh  = (us*)alloc((size_t)NNODE*FIND*2);
  float* FT = (float*)alloc((size_t)NNODE*1280*4);   // fp32 residual cols (1024..1279)
  us* FTB = (us*)alloc((size_t)NNODE*1280*2);        // bf16 feature copy
  float* H2 = (float*)alloc((size_t)NNODE*HD_*4);    // fp32: layer-2 identity residual
  us* H1h = (us*)alloc((size_t)NNODE*HD_*2);
  us* H2h = (us*)alloc((size_t)NNODE*HD_*2);
  us* H3h = (us*)alloc((size_t)NNODE*HD_*2);
  float* Z1 = (float*)alloc((size_t)NNODE*1024*4);

  float* out1 = (float*)d_out;
  float* out2 = out1 + (size_t)NNODE*NC_;

  // ---- weight & input prep ----
  foldT_k<1><<<512, 256, 0, stream>>>(W0, W0h, W0l, 2048, 1024, 32);
  foldT_k<4><<<128, 256, 0, stream>>>(R0, W0h + (size_t)1024*2048, W0l + (size_t)1024*2048, 2048, 256, 32);
  foldT_k<1><<< 64, 256, 0, stream>>>(W1, W1h, W1l, 256, 1024, 4);
  foldT_k<4><<< 16, 256, 0, stream>>>(R1, W1h + (size_t)1024*256, W1l + (size_t)1024*256, 256, 256, 4);
  foldT_k<1><<< 16, 256, 0, stream>>>(W2, W2h, W2l, 256, 256, 4);
  foldT_k<1><<<576, 256, 0, stream>>>(Wl1, WLh, WLl, 2304, 1024, 36);
  bfold_k<<<1, 256, 0, stream>>>(b0, BF0, 4, 256);
  bfold_k<<<1, 256, 0, stream>>>(b1, BF1, 4, 256);
  f2bf1_k<<<(NNODE*FIND/4+255)/256, 256, 0, stream>>>(x, Xh, NNODE*FIND/4);
  rownorm_bf<<<NNODE, 256, 0, stream>>>(x, XNh, XNl);
  valprep_k<4,true ><<<2048, 256, 0, stream>>>(W0, al0, ar0, VAL0, MELG);
  valprep_k<4,false><<< 256, 256, 0, stream>>>(W1, al1, ar1, VALW1, MELG);
  valprep_k<1,false><<<  64, 256, 0, stream>>>(W2, al2, ar2, VALW2, MELG);
  el0gemv_k<<<NNODE, 256, 0, stream>>>(x, VAL0, EL0, ER0, MELG);

  // ---- MEGA: per-XCD role mix 66 Gram + 40 GAT0 + 32 MLP ----
  mega_gemm<<<1104, 256, 0, stream>>>(XNh, XNl, Xh, W0h, W0l, WLh, WLl, FT, FTB, Z1, MASK);

  // ---- GAT layer 0 (emits el/er for layer 1) ----
  sagg_k<4,true,false,8><<<NNODE, 256, 0, stream>>>(FTB, 1280, MASK, EL0, ER0, MELG,
      FT + 1024, 1280, BF0, nullptr, H1h, VALW1, EL1, ER1, MELG + 4);

  // ---- GAT layer 1 (emits el/er for layer 2) ----
  gemm_bf<0><<<320, 256, 0, stream>>>(H1h, W1h, W1l, FT, FTB,
      256, 256, 256, 1280, 10, nullptr, 0.f, 1024, 1024);
  sagg_k<4,true,true,2><<<NNODE, 256, 0, stream>>>(FTB, 1280, MASK, EL1, ER1, MELG + 4,
      FT + 1024, 1280, BF1, H2, H2h, VALW2, EL2c, ER2c, MELG + 8);

  // ---- GAT layer 2 (1 head, identity residual, no relu) ----
  gemm_bf<0><<<64, 256, 0, stream>>>(H2h, W2h, W2l, FT, FTB,
      256, 256, 256, 256, 2, nullptr, 0.f, 1 << 30, 1 << 30);
  sagg_k<1,false,false,0><<<NNODE, 256, 0, stream>>>(FTB, 256, MASK, EL2c, ER2c, MELG + 8,
      H2, 256, b2, nullptr, H3h, nullptr, nullptr, nullptr, nullptr);

  // ---- MLP: Z1 += h3-part, +bias, leaky ----
  gemm_bf<3><<<256, 256, 0, stream>>>(H3h, WLh + 2048, WLl + 2048, Z1, nullptr,
      256, 256, 2304, 1024, 8, bl1, 0.01f, 0, 0);

  head_k<<<NNODE, 256, 0, stream>>>(Z1, 1024, Wc1, bc1, out1);
  head_k<<<NNODE, 256, 0, stream>>>(x, FIND, Wc2, bc2, out2);
}

// Round 12
// 544.274 us; speedup vs baseline: 1.3579x; 1.3579x over previous
//
#include <hip/hip_runtime.h>
#include <cstdint>
#include <cstddef>

#define NNODE 4096
#define FIND  2048
#define HD_   256
#define NC_   10
#define THRESH_ 0.05f
#define LOG2E_ 1.4426950408889634f

typedef unsigned long long u64;
typedef __attribute__((ext_vector_type(8))) short bf16x8;
typedef __attribute__((ext_vector_type(4))) float f32x4;

// ---------- bf16 split helpers ----------
__device__ inline unsigned short f2bf_rne(float f){
  unsigned u = __builtin_bit_cast(unsigned, f);
  unsigned r = u + 0x7FFFu + ((u >> 16) & 1u);
  return (unsigned short)(r >> 16);
}
__device__ inline float bf2f(unsigned short h){
  unsigned u = ((unsigned)h) << 16;
  return __builtin_bit_cast(float, u);
}
__device__ __forceinline__ float fexp2(float x){ return __builtin_amdgcn_exp2f(x); }

// async global->LDS, 16B per lane; lds dest is wave-uniform base (+lane*16 by HW)
__device__ __forceinline__ void gld16(const void* g, void* l){
  __builtin_amdgcn_global_load_lds(
      (const __attribute__((address_space(1))) unsigned int*)g,
      (__attribute__((address_space(3))) unsigned int*)l, 16, 0, 0);
}

// ---------- row normalize -> hi/lo bf16 ----------
__global__ void rownorm_bf(const float* __restrict__ x,
                           unsigned short* __restrict__ oh, unsigned short* __restrict__ ol){
  int row = blockIdx.x; int t = threadIdx.x;
  const float4* xr = reinterpret_cast<const float4*>(x + (size_t)row*FIND);
  float s = 0.f;
  #pragma unroll
  for (int i = 0; i < FIND/4/256; ++i){
    float4 v = xr[t + i*256];
    s += v.x*v.x + v.y*v.y + v.z*v.z + v.w*v.w;
  }
  #pragma unroll
  for (int o = 32; o > 0; o >>= 1) s += __shfl_down(s, o);
  __shared__ float red[4];
  __shared__ float invn;
  if ((t & 63) == 0) red[t >> 6] = s;
  __syncthreads();
  if (t == 0) invn = rsqrtf(red[0] + red[1] + red[2] + red[3]);
  __syncthreads();
  float inv = invn;
  #pragma unroll
  for (int i = 0; i < FIND/4/256; ++i){
    float4 v = xr[t + i*256];
    float a[4] = {v.x*inv, v.y*inv, v.z*inv, v.w*inv};
    ushort4 hv, lv;
    unsigned short* hp = &hv.x; unsigned short* lp = &lv.x;
    #pragma unroll
    for (int j = 0; j < 4; ++j){
      unsigned short h = f2bf_rne(a[j]);
      hp[j] = h; lp[j] = f2bf_rne(a[j] - bf2f(h));
    }
    size_t off = (size_t)row*FIND + (t + i*256)*4;
    *reinterpret_cast<ushort4*>(oh + off) = hv;
    *reinterpret_cast<ushort4*>(ol + off) = lv;
  }
}

// ---------- fp32 -> bf16 hi only (vectorized) ----------
__global__ void f2bf1_k(const float* __restrict__ in, unsigned short* __restrict__ oh, int n4){
  int idx = blockIdx.x*256 + threadIdx.x;
  if (idx >= n4) return;
  float4 v = reinterpret_cast<const float4*>(in)[idx];
  ushort4 hv;
  hv.x = f2bf_rne(v.x); hv.y = f2bf_rne(v.y);
  hv.z = f2bf_rne(v.z); hv.w = f2bf_rne(v.w);
  reinterpret_cast<ushort4*>(oh)[idx] = hv;
}

// ---------- weight prep: R [K, H*F] -> outT [F, K] (sum over H), tiled LDS transpose ----------
template<int H>
__global__ void foldT_k(const float* __restrict__ R, unsigned short* __restrict__ oh,
                        unsigned short* __restrict__ ol, int K, int F, int ktiles){
  int bid = blockIdx.x;
  int f0 = (bid / ktiles) * 64, k0 = (bid % ktiles) * 64;
  __shared__ float tile[64][65];
  int t = threadIdx.x;
  {
    int tf = t & 63, tk4 = t >> 6;
    #pragma unroll
    for (int m = 0; m < 16; ++m){
      int kl = tk4 + m*4;
      float s = 0.f;
      #pragma unroll
      for (int h = 0; h < H; ++h)
        s += R[(size_t)(k0 + kl)*(H*F) + h*F + f0 + tf];
      tile[kl][tf] = s;
    }
  }
  __syncthreads();
  {
    int tk = t & 63, tf4 = t >> 6;
    #pragma unroll
    for (int m = 0; m < 16; ++m){
      int fl = tf4 + m*4;
      float s = tile[tk][fl];
      unsigned short hv = f2bf_rne(s);
      size_t o = (size_t)(f0 + fl)*K + k0 + tk;
      oh[o] = hv;
      ol[o] = f2bf_rne(s - bf2f(hv));
    }
  }
}

__global__ void bfold_k(const float* __restrict__ b, float* __restrict__ out, int H, int F){
  int f = threadIdx.x;
  if (f < F){
    float s = 0.f;
    for (int h = 0; h < H; ++h) s += b[h*F + f];
    out[f] = s;
  }
}

// ---------- attention-vector fold: val[k][h]=sum_f W[k][h*256+f]*al[h][f]; val[k][H+h]=...ar ----------
template<int H>
__global__ void valprep_k(const float* __restrict__ W, const float* __restrict__ al,
                          const float* __restrict__ ar, float* __restrict__ val){
  int t = threadIdx.x, lane = t & 63, w = t >> 6;
  int task = blockIdx.x*4 + w;
  int k = task / H, h = task % H;
  float4 wv = *reinterpret_cast<const float4*>(W + (size_t)k*(H*256) + h*256 + lane*4);
  float4 av = *reinterpret_cast<const float4*>(al + h*256 + lane*4);
  float4 rv = *reinterpret_cast<const float4*>(ar + h*256 + lane*4);
  float e = wv.x*av.x + wv.y*av.y + wv.z*av.z + wv.w*av.w;
  float r = wv.x*rv.x + wv.y*rv.y + wv.z*rv.z + wv.w*rv.w;
  #pragma unroll
  for (int o = 32; o > 0; o >>= 1){ e += __shfl_down(e, o); r += __shfl_down(r, o); }
  if (lane == 0){
    val[(size_t)k*2*H + h] = e;
    val[(size_t)k*2*H + H + h] = r;
  }
}

// ---------- el0/er0 = x @ val0 (x fp32, val0 [2048][8]) ----------
__global__ void el0gemv_k(const float* __restrict__ x, const float* __restrict__ val0,
                          float* __restrict__ el2, float* __restrict__ er2){
  int n = blockIdx.x, t = threadIdx.x;
  float acc[8] = {};
  #pragma unroll
  for (int i = 0; i < 8; ++i){
    int k = i*256 + t;
    float xv = x[(size_t)n*FIND + k];
    float4 v0 = *reinterpret_cast<const float4*>(val0 + (size_t)k*8);
    float4 v1 = *reinterpret_cast<const float4*>(val0 + (size_t)k*8 + 4);
    acc[0] += xv*v0.x; acc[1] += xv*v0.y; acc[2] += xv*v0.z; acc[3] += xv*v0.w;
    acc[4] += xv*v1.x; acc[5] += xv*v1.y; acc[6] += xv*v1.z; acc[7] += xv*v1.w;
  }
  __shared__ float red[4][8];
  #pragma unroll
  for (int j = 0; j < 8; ++j){
    float v = acc[j];
    #pragma unroll
    for (int o = 32; o > 0; o >>= 1) v += __shfl_down(v, o);
    if ((t & 63) == 0) red[t >> 6][j] = v;
  }
  __syncthreads();
  if (t < 4){
    int h = t;
    el2[(size_t)n*4 + h] = (red[0][h] + red[1][h] + red[2][h] + red[3][h]) * LOG2E_;
    er2[(size_t)n*4 + h] = (red[0][4+h] + red[1][4+h] + red[2][4+h] + red[3][4+h]) * LOG2E_;
  }
}

// ---------- global max of el2 per head (upper bound for softmax subtract), no atomics ----------
template<int H>
__global__ void elmax_k(const float* __restrict__ el2, float* __restrict__ out){
  int h = blockIdx.x, t = threadIdx.x;
  float m = -1e30f;
  for (int n = t; n < NNODE; n += 256) m = fmaxf(m, el2[(size_t)n*H + h]);
  #pragma unroll
  for (int o = 32; o > 0; o >>= 1) m = fmaxf(m, __shfl_down(m, o));
  __shared__ float red[4];
  if ((t & 63) == 0) red[t >> 6] = m;
  __syncthreads();
  if (t == 0) out[h] = fmaxf(fmaxf(red[0], red[1]), fmaxf(red[2], red[3]));
}

// ---------- MEGA GEMM: role-interleaved per XCD (load-balanced) ----------
// 1104 blocks = 8 XCDs x 138. Per XCD: 66 Gram(3-term) + 40 GAT0(2-term) + 32 MLP(2-term).
__global__ void mega_gemm(const unsigned short* __restrict__ XNh, const unsigned short* __restrict__ XNl,
                          const unsigned short* __restrict__ Xh,
                          const unsigned short* __restrict__ W0h, const unsigned short* __restrict__ W0l,
                          const unsigned short* __restrict__ WLh, const unsigned short* __restrict__ WLl,
                          float* __restrict__ FT, unsigned short* __restrict__ FTB,
                          float* __restrict__ Z1, u64* __restrict__ Mk){
  __shared__ unsigned short smem[4*128*32];
  unsigned short* sAh = smem;
  unsigned short* sAl = smem + 4096;
  unsigned short* sBh = smem + 8192;
  unsigned short* sBl = smem + 12288;
  const int t = threadIdx.x, lane = t & 63, w = t >> 6;
  const int wr = w >> 1, wc = w & 1, l15 = lane & 15, lg = lane >> 4;

  const int bid = blockIdx.x;
  const int xcd = bid & 7, idx = bid >> 3;   // blocks round-robin to XCDs by bid&7

  int role, brow, bcol;
  const unsigned short *Ah, *Al = nullptr, *Bh, *Bl;
  float* C = nullptr; int ldc = 0; size_t ldb;
  if (idx < 66){
    role = 0;
    int g = xcd*66 + idx;                    // 0..527 upper-tri
    int rem = g, i = 0;
    while (rem >= 32 - i){ rem -= 32 - i; ++i; }
    brow = i; bcol = i + rem;
    Ah = XNh; Al = XNl; Bh = XNh; Bl = XNl; ldb = FIND;
  } else if (idx < 106){
    role = 1;
    int l = xcd*40 + (idx - 66);             // 0..319
    brow = l / 10; bcol = l % 10;
    Ah = Xh; Bh = W0h; Bl = W0l; ldb = FIND;
    C = FT; ldc = 1280;
  } else {
    role = 2;
    int l = xcd*32 + (idx - 106);            // 0..255
    brow = l >> 3; bcol = l & 7;
    Ah = Xh; Bh = WLh; Bl = WLl; ldb = 2304;
    C = Z1; ldc = 1024;
  }
  const bool three = (role == 0);
  const int row0 = brow*128, col0 = bcol*128;

  const int c0 = 2*w, c1 = 2*w + 1;
  const int rsub = lane >> 2, piece = lane & 3;
  const size_t ld2a = (size_t)FIND*2, ld2b = ldb*2;
  const size_t a0 = (size_t)(row0 + 16*c0 + rsub)*ld2a + piece*16;
  const size_t a1 = (size_t)(row0 + 16*c1 + rsub)*ld2a + piece*16;
  const size_t b0 = (size_t)(col0 + 16*c0 + rsub)*ld2b + piece*16;
  const size_t b1 = (size_t)(col0 + 16*c1 + rsub)*ld2b + piece*16;
  const char* pA0h = (const char*)Ah + a0;  const char* pA1h = (const char*)Ah + a1;
  const char* pA0l = three ? (const char*)Al + a0 : nullptr;
  const char* pA1l = three ? (const char*)Al + a1 : nullptr;
  const char* pB0h = (const char*)Bh + b0;  const char* pB1h = (const char*)Bh + b1;
  const char* pB0l = (const char*)Bl + b0;  const char* pB1l = (const char*)Bl + b1;
  char* lA0h = (char*)sAh + c0*1024;  char* lA1h = (char*)sAh + c1*1024;
  char* lA0l = (char*)sAl + c0*1024;  char* lA1l = (char*)sAl + c1*1024;
  char* lB0h = (char*)sBh + c0*1024;  char* lB1h = (char*)sBh + c1*1024;
  char* lB0l = (char*)sBl + c0*1024;  char* lB1l = (char*)sBl + c1*1024;

  f32x4 acc[4][4] = {};
  for (int kt = 0; kt < 64; ++kt){
    __syncthreads();
    gld16(pA0h, lA0h); gld16(pA1h, lA1h);
    if (three){
      gld16(pA0l, lA0l); gld16(pA1l, lA1l);
      pA0l += 64; pA1l += 64;
    }
    gld16(pB0h, lB0h); gld16(pB1h, lB1h);
    gld16(pB0l, lB0l); gld16(pB1l, lB1l);
    pA0h += 64; pA1h += 64;
    pB0h += 64; pB1h += 64; pB0l += 64; pB1l += 64;
    __syncthreads();
    bf16x8 fb_h[4], fb_l[4];
    #pragma unroll
    for (int j = 0; j < 4; ++j){
      int bo = (wc*64 + j*16 + l15)*32 + lg*8;
      fb_h[j] = *reinterpret_cast<const bf16x8*>(sBh + bo);
      fb_l[j] = *reinterpret_cast<const bf16x8*>(sBl + bo);
    }
    #pragma unroll
    for (int i = 0; i < 4; ++i){
      int ao = (wr*64 + i*16 + l15)*32 + lg*8;
      bf16x8 fah = *reinterpret_cast<const bf16x8*>(sAh + ao);
      #pragma unroll
      for (int j = 0; j < 4; ++j){
        acc[i][j] = __builtin_amdgcn_mfma_f32_16x16x32_bf16(fah, fb_h[j], acc[i][j], 0, 0, 0);
        acc[i][j] = __builtin_amdgcn_mfma_f32_16x16x32_bf16(fah, fb_l[j], acc[i][j], 0, 0, 0);
      }
      if (three){
        bf16x8 fal = *reinterpret_cast<const bf16x8*>(sAl + ao);
        #pragma unroll
        for (int j = 0; j < 4; ++j)
          acc[i][j] = __builtin_amdgcn_mfma_f32_16x16x32_bf16(fal, fb_h[j], acc[i][j], 0, 0, 0);
      }
    }
  }

  if (role == 0){
    #pragma unroll
    for (int i = 0; i < 4; ++i){
      #pragma unroll
      for (int r = 0; r < 4; ++r){
        u64 bits = 0ull;
        #pragma unroll
        for (int j = 0; j < 4; ++j)
          if (acc[i][j][r] > THRESH_) bits |= 1ull << (j*16 + l15);
        #pragma unroll
        for (int m = 1; m <= 8; m <<= 1) bits |= __shfl_xor(bits, m);
        if (l15 == 0){
          int gr = row0 + wr*64 + i*16 + lg*4 + r;
          Mk[(size_t)gr*64 + (col0 >> 6) + wc] = bits;
        }
      }
    }
    if (row0 != col0){
      #pragma unroll
      for (int j = 0; j < 4; ++j){
        u64 tb = 0ull;
        #pragma unroll
        for (int i = 0; i < 4; ++i)
          #pragma unroll
          for (int r = 0; r < 4; ++r)
            if (acc[i][j][r] > THRESH_) tb |= 1ull << (i*16 + lg*4 + r);
        tb |= __shfl_xor(tb, 16);
        tb |= __shfl_xor(tb, 32);
        if (lg == 0){
          int gc = col0 + wc*64 + j*16 + l15;
          Mk[(size_t)gc*64 + (row0 >> 6) + wr] = tb;
        }
      }
    }
  } else {
    const int f32min = (role == 1) ? 1024 : 0;   // role1: fp32 only residual cols
    #pragma unroll
    for (int i = 0; i < 4; ++i){
      int gr = row0 + wr*64 + i*16 + lg*4;
      #pragma unroll
      for (int j = 0; j < 4; ++j){
        int gc = col0 + wc*64 + j*16 + l15;
        #pragma unroll
        for (int r = 0; r < 4; ++r){
          float v = acc[i][j][r];
          if (role == 1 && gc < 1024) FTB[(size_t)(gr + r)*1280 + gc] = f2bf_rne(v);
          if (gc >= f32min) C[(size_t)(gr + r)*ldc + gc] = v;
        }
      }
    }
  }
}

// ---------- 2-term MFMA NT GEMM (A-hi only; B hi+lo) for short-K layers ----------
// EPI: 0 = store (Cb bf16 where gc<bfmax; C fp32 where gc>=f32min); 3 = C += acc,+bias,leaky
template<int EPI>
__global__ void gemm_bf(const unsigned short* __restrict__ Ah,
                        const unsigned short* __restrict__ Bh, const unsigned short* __restrict__ Bl,
                        float* __restrict__ C, unsigned short* __restrict__ Cb,
                        int K, int lda, int ldb, int ldc, int gridx,
                        const float* __restrict__ bias, float param, int f32min, int bfmax){
  __shared__ unsigned short smem[3*128*32];
  unsigned short* sAh = smem;
  unsigned short* sBh = smem + 4096;
  unsigned short* sBl = smem + 8192;
  const int t = threadIdx.x, lane = t & 63, w = t >> 6;
  const int wr = w >> 1, wc = w & 1, l15 = lane & 15, lg = lane >> 4;

  int nwg = gridDim.x, bid = blockIdx.x;
  int wg = ((nwg & 7) == 0) ? ((bid & 7)*(nwg >> 3) + (bid >> 3)) : bid;
  int brow = wg / gridx, bcol = wg % gridx;
  const int row0 = brow*128, col0 = bcol*128;

  const int c0 = 2*w, c1 = 2*w + 1;
  const int rsub = lane >> 2, piece = lane & 3;
  const size_t ld2a = (size_t)lda*2, ld2b = (size_t)ldb*2;
  const size_t a0 = (size_t)(row0 + 16*c0 + rsub)*ld2a + piece*16;
  const size_t a1 = (size_t)(row0 + 16*c1 + rsub)*ld2a + piece*16;
  const size_t b0 = (size_t)(col0 + 16*c0 + rsub)*ld2b + piece*16;
  const size_t b1 = (size_t)(col0 + 16*c1 + rsub)*ld2b + piece*16;
  const char* pA0h = (const char*)Ah + a0;  const char* pA1h = (const char*)Ah + a1;
  const char* pB0h = (const char*)Bh + b0;  const char* pB1h = (const char*)Bh + b1;
  const char* pB0l = (const char*)Bl + b0;  const char* pB1l = (const char*)Bl + b1;
  char* lA0h = (char*)sAh + c0*1024;  char* lA1h = (char*)sAh + c1*1024;
  char* lB0h = (char*)sBh + c0*1024;  char* lB1h = (char*)sBh + c1*1024;
  char* lB0l = (char*)sBl + c0*1024;  char* lB1l = (char*)sBl + c1*1024;

  f32x4 acc[4][4] = {};
  const int nk = K >> 5;
  for (int kt = 0; kt < nk; ++kt){
    __syncthreads();
    gld16(pA0h, lA0h); gld16(pA1h, lA1h);
    gld16(pB0h, lB0h); gld16(pB1h, lB1h);
    gld16(pB0l, lB0l); gld16(pB1l, lB1l);
    pA0h += 64; pA1h += 64;
    pB0h += 64; pB1h += 64; pB0l += 64; pB1l += 64;
    __syncthreads();
    bf16x8 fb_h[4], fb_l[4];
    #pragma unroll
    for (int j = 0; j < 4; ++j){
      int bo = (wc*64 + j*16 + l15)*32 + lg*8;
      fb_h[j] = *reinterpret_cast<const bf16x8*>(sBh + bo);
      fb_l[j] = *reinterpret_cast<const bf16x8*>(sBl + bo);
    }
    #pragma unroll
    for (int i = 0; i < 4; ++i){
      int ao = (wr*64 + i*16 + l15)*32 + lg*8;
      bf16x8 fah = *reinterpret_cast<const bf16x8*>(sAh + ao);
      #pragma unroll
      for (int j = 0; j < 4; ++j){
        acc[i][j] = __builtin_amdgcn_mfma_f32_16x16x32_bf16(fah, fb_h[j], acc[i][j], 0, 0, 0);
        acc[i][j] = __builtin_amdgcn_mfma_f32_16x16x32_bf16(fah, fb_l[j], acc[i][j], 0, 0, 0);
      }
    }
  }

  #pragma unroll
  for (int i = 0; i < 4; ++i){
    int gr = row0 + wr*64 + i*16 + lg*4;
    #pragma unroll
    for (int j = 0; j < 4; ++j){
      int gc = col0 + wc*64 + j*16 + l15;
      #pragma unroll
      for (int r = 0; r < 4; ++r){
        float v = acc[i][j][r];
        size_t o = (size_t)(gr + r)*ldc + gc;
        if (EPI == 3){
          v += C[o] + bias[gc];
          v = v > 0.f ? v : param*v;
          C[o] = v;
        } else {
          if (gc < bfmax) Cb[o] = f2bf_rne(v);
          if (gc >= f32min) C[o] = v;
        }
      }
    }
  }
}

// ---------- single-pass softmax aggregation (bf16 gather, unmasked-max bound) ----------
// NEXTJ: 8 -> emit next-layer el/er (4 heads) via valw; 2 -> 1 head; 0 -> none.
template<int H, bool RELU, bool OUTF32, int NEXTJ>
__global__ void sagg_k(const unsigned short* __restrict__ FTB, int ldf,
                       const u64* __restrict__ Mk,
                       const float* __restrict__ el2, const float* __restrict__ er2,
                       const float* __restrict__ melg,
                       const float* __restrict__ res, int ldres,
                       const float* __restrict__ bias,
                       float* __restrict__ outf,
                       unsigned short* __restrict__ oh,
                       const float* __restrict__ valw,
                       float* __restrict__ el2n, float* __restrict__ er2n){
  int d = blockIdx.x, t = threadIdx.x;
  const int g = t >> 6, q = t & 63;
  const int h = (H == 4) ? g : 0;
  const int wlo = (H == 1) ? g*16 : 0;
  const int whi = (H == 1) ? wlo + 16 : 64;
  const float er2d = er2[(size_t)d*H + h];
  const float sub = er2d + melg[h];
  const float m2 = fmaxf(sub, 0.2f*sub);   // >= all masked scores (leaky monotone)
  const unsigned short* fb = FTB + 4*q + ((H == 4) ? 256*g : 0);
  float4 acc = {0.f, 0.f, 0.f, 0.f};
  float sm = 0.f;
  for (int wdi = wlo; wdi < whi; ++wdi){
    u64 bits = Mk[(size_t)d*64 + wdi];
    while (bits){
      int b = __builtin_ctzll(bits);
      bits &= bits - 1ull;
      int s = wdi*64 + b;
      float sc = er2d + el2[(size_t)s*H + h];
      sc = fmaxf(sc, 0.2f*sc);
      float wt = fexp2(sc - m2);
      sm += wt;
      ushort4 v = *reinterpret_cast<const ushort4*>(fb + (size_t)s*ldf);
      acc.x += wt*bf2f(v.x); acc.y += wt*bf2f(v.y);
      acc.z += wt*bf2f(v.z); acc.w += wt*bf2f(v.w);
    }
  }
  __shared__ float lred[4][256];
  __shared__ float lsm[4];
  if (H == 4){
    float inv = 1.f / sm;    // sm identical across the head's 64 lanes
    acc.x *= inv; acc.y *= inv; acc.z *= inv; acc.w *= inv;
  } else if (q == 0){
    lsm[g] = sm;
  }
  lred[g][q*4+0] = acc.x; lred[g][q*4+1] = acc.y;
  lred[g][q*4+2] = acc.z; lred[g][q*4+3] = acc.w;
  __syncthreads();
  float v = ((lred[0][t] + lred[1][t]) + lred[2][t]) + lred[3][t];
  if (H == 1) v /= (lsm[0] + lsm[1]) + (lsm[2] + lsm[3]);
  v += res[(size_t)d*ldres + t] + bias[t];
  if (RELU) v = fmaxf(v, 0.f);
  if (OUTF32) outf[(size_t)d*HD_ + t] = v;
  oh[(size_t)d*HD_ + t] = f2bf_rne(v);

  // ---- fused next-layer el/er: el_n[d,h] = sum_t v * valw[t][h] (plain stores, no atomics) ----
  if (NEXTJ > 0){
    float p[NEXTJ > 0 ? NEXTJ : 1];
    if (NEXTJ == 8){
      float4 w0 = *reinterpret_cast<const float4*>(valw + (size_t)t*8);
      float4 w1 = *reinterpret_cast<const float4*>(valw + (size_t)t*8 + 4);
      p[0] = v*w0.x; p[1] = v*w0.y; p[2] = v*w0.z; p[3] = v*w0.w;
      p[4] = v*w1.x; p[5] = v*w1.y; p[6] = v*w1.z; p[7] = v*w1.w;
    } else if (NEXTJ == 2){
      float2 w0 = *reinterpret_cast<const float2*>(valw + (size_t)t*2);
      p[0] = v*w0.x; p[1] = v*w0.y;
    }
    __shared__ float ered[4][NEXTJ > 0 ? NEXTJ : 1];
    #pragma unroll
    for (int j = 0; j < NEXTJ; ++j){
      float pv = p[j];
      #pragma unroll
      for (int o = 32; o > 0; o >>= 1) pv += __shfl_down(pv, o);
      if (q == 0) ered[g][j] = pv;
    }
    __syncthreads();
    const int NH = NEXTJ/2;
    if (t < NH){
      int hh = t;
      el2n[(size_t)d*NH + hh] = (ered[0][hh] + ered[1][hh] + ered[2][hh] + ered[3][hh]) * LOG2E_;
      er2n[(size_t)d*NH + hh] = (ered[0][NH+hh] + ered[1][NH+hh] + ered[2][NH+hh] + ered[3][NH+hh]) * LOG2E_;
    }
  }
}

// ---------- classifier head ----------
__global__ void head_k(const float* __restrict__ A, int K, const float* __restrict__ W,
                       const float* __restrict__ b, float* __restrict__ out){
  int row = blockIdx.x, t = threadIdx.x;
  float p[NC_];
  #pragma unroll
  for (int j = 0; j < NC_; ++j) p[j] = 0.f;
  for (int k = t; k < K; k += 256){
    float a = A[(size_t)row*K + k];
    #pragma unroll
    for (int j = 0; j < NC_; ++j) p[j] += a * W[k*NC_ + j];
  }
  #pragma unroll
  for (int j = 0; j < NC_; ++j){
    #pragma unroll
    for (int o = 32; o > 0; o >>= 1) p[j] += __shfl_down(p[j], o);
  }
  __shared__ float red[4][NC_];
  if ((t & 63) == 0){
    #pragma unroll
    for (int j = 0; j < NC_; ++j) red[t >> 6][j] = p[j];
  }
  __syncthreads();
  if (t < NC_)
    out[(size_t)row*NC_ + t] = red[0][t] + red[1][t] + red[2][t] + red[3][t] + b[t];
}

// ---------- launch ----------
extern "C" void kernel_launch(void* const* d_in, const int* in_sizes, int n_in,
                              void* d_out, int out_size, void* d_ws, size_t ws_size,
                              hipStream_t stream){
  const float* x   = (const float*)d_in[0];
  const float* W0  = (const float*)d_in[1];
  const float* al0 = (const float*)d_in[2];
  const float* ar0 = (const float*)d_in[3];
  const float* b0  = (const float*)d_in[4];
  const float* R0  = (const float*)d_in[5];
  const float* W1  = (const float*)d_in[6];
  const float* al1 = (const float*)d_in[7];
  const float* ar1 = (const float*)d_in[8];
  const float* b1  = (const float*)d_in[9];
  const float* R1  = (const float*)d_in[10];
  const float* W2  = (const float*)d_in[11];
  const float* al2 = (const float*)d_in[12];
  const float* ar2 = (const float*)d_in[13];
  const float* b2  = (const float*)d_in[14];
  const float* Wl1 = (const float*)d_in[15];
  const float* bl1 = (const float*)d_in[16];
  const float* Wc1 = (const float*)d_in[17];
  const float* bc1 = (const float*)d_in[18];
  const float* Wc2 = (const float*)d_in[19];
  const float* bc2 = (const float*)d_in[20];
  (void)in_sizes; (void)n_in; (void)out_size; (void)ws_size;

  char* ws = (char*)d_ws;
  size_t off = 0;
  auto alloc = [&](size_t bytes)->char*{
    char* p = ws + off; off += (bytes + 255) & ~(size_t)255; return p;
  };
  typedef unsigned short us;
  u64* MASK = (u64*)alloc((size_t)NNODE*64*8);
  us* W0h = (us*)alloc((size_t)1280*2048*2);  us* W0l = (us*)alloc((size_t)1280*2048*2);
  us* W1h = (us*)alloc((size_t)1280*256*2);   us* W1l = (us*)alloc((size_t)1280*256*2);
  us* W2h = (us*)alloc((size_t)256*256*2);    us* W2l = (us*)alloc((size_t)256*256*2);
  us* WLh = (us*)alloc((size_t)1024*2304*2);  us* WLl = (us*)alloc((size_t)1024*2304*2);
  float* BF0 = (float*)alloc(256*4);
  float* BF1 = (float*)alloc(256*4);
  float* VAL0 = (float*)alloc((size_t)2048*8*4);
  float* VALW1 = (float*)alloc((size_t)256*8*4);
  float* VALW2 = (float*)alloc((size_t)256*2*4);
  float* EL0 = (float*)alloc((size_t)NNODE*4*4);
  float* ER0 = (float*)alloc((size_t)NNODE*4*4);
  float* EL1 = (float*)alloc((size_t)NNODE*4*4);
  float* ER1 = (float*)alloc((size_t)NNODE*4*4);
  float* EL2c = (float*)alloc((size_t)NNODE*4);
  float* ER2c = (float*)alloc((size_t)NNODE*4);
  float* MELG = (float*)alloc(12*4);   // [0..3]=L0, [4..7]=L1, [8]=L2
  us* XNh = (us*)alloc((size_t)NNODE*FIND*2);
  us* XNl = (us*)alloc((size_t)NNODE*FIND*2);
  us* Xh  = (us*)alloc((size_t)NNODE*FIND*2);
  float* FT = (float*)alloc((size_t)NNODE*1280*4);   // fp32 residual cols (1024..1279)
  us* FTB = (us*)alloc((size_t)NNODE*1280*2);        // bf16 feature copy
  float* H2 = (float*)alloc((size_t)NNODE*HD_*4);    // fp32: layer-2 identity residual
  us* H1h = (us*)alloc((size_t)NNODE*HD_*2);
  us* H2h = (us*)alloc((size_t)NNODE*HD_*2);
  us* H3h = (us*)alloc((size_t)NNODE*HD_*2);
  float* Z1 = (float*)alloc((size_t)NNODE*1024*4);

  float* out1 = (float*)d_out;
  float* out2 = out1 + (size_t)NNODE*NC_;

  // ---- weight & input prep ----
  foldT_k<1><<<512, 256, 0, stream>>>(W0, W0h, W0l, 2048, 1024, 32);
  foldT_k<4><<<128, 256, 0, stream>>>(R0, W0h + (size_t)1024*2048, W0l + (size_t)1024*2048, 2048, 256, 32);
  foldT_k<1><<< 64, 256, 0, stream>>>(W1, W1h, W1l, 256, 1024, 4);
  foldT_k<4><<< 16, 256, 0, stream>>>(R1, W1h + (size_t)1024*256, W1l + (size_t)1024*256, 256, 256, 4);
  foldT_k<1><<< 16, 256, 0, stream>>>(W2, W2h, W2l, 256, 256, 4);
  foldT_k<1><<<576, 256, 0, stream>>>(Wl1, WLh, WLl, 2304, 1024, 36);
  bfold_k<<<1, 256, 0, stream>>>(b0, BF0, 4, 256);
  bfold_k<<<1, 256, 0, stream>>>(b1, BF1, 4, 256);
  f2bf1_k<<<(NNODE*FIND/4+255)/256, 256, 0, stream>>>(x, Xh, NNODE*FIND/4);
  rownorm_bf<<<NNODE, 256, 0, stream>>>(x, XNh, XNl);
  valprep_k<4><<<2048, 256, 0, stream>>>(W0, al0, ar0, VAL0);
  valprep_k<4><<< 256, 256, 0, stream>>>(W1, al1, ar1, VALW1);
  valprep_k<1><<<  64, 256, 0, stream>>>(W2, al2, ar2, VALW2);
  el0gemv_k<<<NNODE, 256, 0, stream>>>(x, VAL0, EL0, ER0);
  elmax_k<4><<<4, 256, 0, stream>>>(EL0, MELG);

  // ---- MEGA: per-XCD role mix 66 Gram + 40 GAT0 + 32 MLP ----
  mega_gemm<<<1104, 256, 0, stream>>>(XNh, XNl, Xh, W0h, W0l, WLh, WLl, FT, FTB, Z1, MASK);

  // ---- GAT layer 0 (emits el/er for layer 1) ----
  sagg_k<4,true,false,8><<<NNODE, 256, 0, stream>>>(FTB, 1280, MASK, EL0, ER0, MELG,
      FT + 1024, 1280, BF0, nullptr, H1h, VALW1, EL1, ER1);
  elmax_k<4><<<4, 256, 0, stream>>>(EL1, MELG + 4);

  // ---- GAT layer 1 (emits el/er for layer 2) ----
  gemm_bf<0><<<320, 256, 0, stream>>>(H1h, W1h, W1l, FT, FTB,
      256, 256, 256, 1280, 10, nullptr, 0.f, 1024, 1024);
  sagg_k<4,true,true,2><<<NNODE, 256, 0, stream>>>(FTB, 1280, MASK, EL1, ER1, MELG + 4,
      FT + 1024, 1280, BF1, H2, H2h, VALW2, EL2c, ER2c);
  elmax_k<1><<<1, 256, 0, stream>>>(EL2c, MELG + 8);

  // ---- GAT layer 2 (1 head, identity residual, no relu) ----
  gemm_bf<0><<<64, 256, 0, stream>>>(H2h, W2h, W2l, FT, FTB,
      256, 256, 256, 256, 2, nullptr, 0.f, 1 << 30, 1 << 30);
  sagg_k<1,false,false,0><<<NNODE, 256, 0, stream>>>(FTB, 256, MASK, EL2c, ER2c, MELG + 8,
      H2, 256, b2, nullptr, H3h, nullptr, nullptr, nullptr);

  // ---- MLP: Z1 += h3-part, +bias, leaky ----
  gemm_bf<3><<<256, 256, 0, stream>>>(H3h, WLh + 2048, WLl + 2048, Z1, nullptr,
      256, 256, 2304, 1024, 8, bl1, 0.01f, 0, 0);

  head_k<<<NNODE, 256, 0, stream>>>(Z1, 1024, Wc1, bc1, out1);
  head_k<<<NNODE, 256, 0, stream>>>(x, FIND, Wc2, bc2, out2);
}

// Round 13
// 530.644 us; speedup vs baseline: 1.3928x; 1.0257x over previous
//
#include <hip/hip_runtime.h>
#include <cstdint>
#include <cstddef>

#define NNODE 4096
#define FIND  2048
#define HD_   256
#define NC_   10
#define THRESH_ 0.05f
#define LOG2E_ 1.4426950408889634f

typedef unsigned long long u64;
typedef __attribute__((ext_vector_type(8))) short bf16x8;
typedef __attribute__((ext_vector_type(4))) float f32x4;

// ---------- bf16 split helpers ----------
__device__ inline unsigned short f2bf_rne(float f){
  unsigned u = __builtin_bit_cast(unsigned, f);
  unsigned r = u + 0x7FFFu + ((u >> 16) & 1u);
  return (unsigned short)(r >> 16);
}
__device__ inline float bf2f(unsigned short h){
  unsigned u = ((unsigned)h) << 16;
  return __builtin_bit_cast(float, u);
}
__device__ __forceinline__ float fexp2(float x){ return __builtin_amdgcn_exp2f(x); }

// async global->LDS, 16B per lane; lds dest is wave-uniform base (+lane*16 by HW)
__device__ __forceinline__ void gld16(const void* g, void* l){
  __builtin_amdgcn_global_load_lds(
      (const __attribute__((address_space(1))) unsigned int*)g,
      (__attribute__((address_space(3))) unsigned int*)l, 16, 0, 0);
}

// ---------- fused x prep: Xh (bf16), XNh/XNl (normalized hi/lo), el0/er0 ----------
// One read of x replaces f2bf1_k + rownorm_bf + el0gemv_k.
__global__ void xprep_k(const float* __restrict__ x, const float* __restrict__ val0,
                        unsigned short* __restrict__ Xh,
                        unsigned short* __restrict__ XNh, unsigned short* __restrict__ XNl,
                        float* __restrict__ el2, float* __restrict__ er2){
  int row = blockIdx.x, t = threadIdx.x;
  float xv[8];
  float s = 0.f;
  float acc[8] = {};
  #pragma unroll
  for (int i = 0; i < 8; ++i){
    int k = t + i*256;
    float v = x[(size_t)row*FIND + k];
    xv[i] = v;
    s += v*v;
    float4 v0 = *reinterpret_cast<const float4*>(val0 + (size_t)k*8);
    float4 v1 = *reinterpret_cast<const float4*>(val0 + (size_t)k*8 + 4);
    acc[0] += v*v0.x; acc[1] += v*v0.y; acc[2] += v*v0.z; acc[3] += v*v0.w;
    acc[4] += v*v1.x; acc[5] += v*v1.y; acc[6] += v*v1.z; acc[7] += v*v1.w;
    Xh[(size_t)row*FIND + k] = f2bf_rne(v);
  }
  __shared__ float redS[4];
  __shared__ float redA[4][8];
  __shared__ float invn;
  #pragma unroll
  for (int o = 32; o > 0; o >>= 1) s += __shfl_down(s, o);
  #pragma unroll
  for (int j = 0; j < 8; ++j){
    float v = acc[j];
    #pragma unroll
    for (int o = 32; o > 0; o >>= 1) v += __shfl_down(v, o);
    if ((t & 63) == 0) redA[t >> 6][j] = v;
  }
  if ((t & 63) == 0) redS[t >> 6] = s;
  __syncthreads();
  if (t == 0) invn = rsqrtf(redS[0] + redS[1] + redS[2] + redS[3]);
  if (t < 4){
    int h = t;
    el2[(size_t)row*4 + h] = (redA[0][h] + redA[1][h] + redA[2][h] + redA[3][h]) * LOG2E_;
    er2[(size_t)row*4 + h] = (redA[0][4+h] + redA[1][4+h] + redA[2][4+h] + redA[3][4+h]) * LOG2E_;
  }
  __syncthreads();
  float inv = invn;
  #pragma unroll
  for (int i = 0; i < 8; ++i){
    int k = t + i*256;
    float a = xv[i]*inv;
    unsigned short h = f2bf_rne(a);
    XNh[(size_t)row*FIND + k] = h;
    XNl[(size_t)row*FIND + k] = f2bf_rne(a - bf2f(h));
  }
}

// ---------- weight prep: R [K, H*F] -> outT [F, K] (sum over H), tiled LDS transpose ----------
template<int H>
__global__ void foldT_k(const float* __restrict__ R, unsigned short* __restrict__ oh,
                        unsigned short* __restrict__ ol, int K, int F, int ktiles){
  int bid = blockIdx.x;
  int f0 = (bid / ktiles) * 64, k0 = (bid % ktiles) * 64;
  __shared__ float tile[64][65];
  int t = threadIdx.x;
  {
    int tf = t & 63, tk4 = t >> 6;
    #pragma unroll
    for (int m = 0; m < 16; ++m){
      int kl = tk4 + m*4;
      float s = 0.f;
      #pragma unroll
      for (int h = 0; h < H; ++h)
        s += R[(size_t)(k0 + kl)*(H*F) + h*F + f0 + tf];
      tile[kl][tf] = s;
    }
  }
  __syncthreads();
  {
    int tk = t & 63, tf4 = t >> 6;
    #pragma unroll
    for (int m = 0; m < 16; ++m){
      int fl = tf4 + m*4;
      float s = tile[tk][fl];
      unsigned short hv = f2bf_rne(s);
      size_t o = (size_t)(f0 + fl)*K + k0 + tk;
      oh[o] = hv;
      ol[o] = f2bf_rne(s - bf2f(hv));
    }
  }
}

__global__ void bfold_k(const float* __restrict__ b, float* __restrict__ out, int H, int F){
  int f = threadIdx.x;
  if (f < F){
    float s = 0.f;
    for (int h = 0; h < H; ++h) s += b[h*F + f];
    out[f] = s;
  }
}

// ---------- attention-vector fold: val[k][h]=sum_f W[k][h*256+f]*al[h][f]; val[k][H+h]=...ar ----------
template<int H>
__global__ void valprep_k(const float* __restrict__ W, const float* __restrict__ al,
                          const float* __restrict__ ar, float* __restrict__ val){
  int t = threadIdx.x, lane = t & 63, w = t >> 6;
  int task = blockIdx.x*4 + w;
  int k = task / H, h = task % H;
  float4 wv = *reinterpret_cast<const float4*>(W + (size_t)k*(H*256) + h*256 + lane*4);
  float4 av = *reinterpret_cast<const float4*>(al + h*256 + lane*4);
  float4 rv = *reinterpret_cast<const float4*>(ar + h*256 + lane*4);
  float e = wv.x*av.x + wv.y*av.y + wv.z*av.z + wv.w*av.w;
  float r = wv.x*rv.x + wv.y*rv.y + wv.z*rv.z + wv.w*rv.w;
  #pragma unroll
  for (int o = 32; o > 0; o >>= 1){ e += __shfl_down(e, o); r += __shfl_down(r, o); }
  if (lane == 0){
    val[(size_t)k*2*H + h] = e;
    val[(size_t)k*2*H + H + h] = r;
  }
}

// ---------- global max of el2 per head (upper bound for softmax subtract), no atomics ----------
template<int H>
__global__ void elmax_k(const float* __restrict__ el2, float* __restrict__ out){
  int h = blockIdx.x, t = threadIdx.x;
  float m = -1e30f;
  for (int n = t; n < NNODE; n += 256) m = fmaxf(m, el2[(size_t)n*H + h]);
  #pragma unroll
  for (int o = 32; o > 0; o >>= 1) m = fmaxf(m, __shfl_down(m, o));
  __shared__ float red[4];
  if ((t & 63) == 0) red[t >> 6] = m;
  __syncthreads();
  if (t == 0) out[h] = fmaxf(fmaxf(red[0], red[1]), fmaxf(red[2], red[3]));
}

// ---------- MEGA GEMM: role-interleaved per XCD (load-balanced) ----------
// 1104 blocks = 8 XCDs x 138. Per XCD: 66 Gram(3-term) + 40 GAT0(2-term) + 32 MLP(2-term).
__global__ void mega_gemm(const unsigned short* __restrict__ XNh, const unsigned short* __restrict__ XNl,
                          const unsigned short* __restrict__ Xh,
                          const unsigned short* __restrict__ W0h, const unsigned short* __restrict__ W0l,
                          const unsigned short* __restrict__ WLh, const unsigned short* __restrict__ WLl,
                          float* __restrict__ FT, unsigned short* __restrict__ FTB,
                          float* __restrict__ Z1, u64* __restrict__ Mk){
  __shared__ unsigned short smem[4*128*32];
  unsigned short* sAh = smem;
  unsigned short* sAl = smem + 4096;
  unsigned short* sBh = smem + 8192;
  unsigned short* sBl = smem + 12288;
  const int t = threadIdx.x, lane = t & 63, w = t >> 6;
  const int wr = w >> 1, wc = w & 1, l15 = lane & 15, lg = lane >> 4;

  const int bid = blockIdx.x;
  const int xcd = bid & 7, idx = bid >> 3;   // blocks round-robin to XCDs by bid&7

  int role, brow, bcol;
  const unsigned short *Ah, *Al = nullptr, *Bh, *Bl;
  float* C = nullptr; int ldc = 0; size_t ldb;
  if (idx < 66){
    role = 0;
    int g = xcd*66 + idx;                    // 0..527 upper-tri
    int rem = g, i = 0;
    while (rem >= 32 - i){ rem -= 32 - i; ++i; }
    brow = i; bcol = i + rem;
    Ah = XNh; Al = XNl; Bh = XNh; Bl = XNl; ldb = FIND;
  } else if (idx < 106){
    role = 1;
    int l = xcd*40 + (idx - 66);             // 0..319
    brow = l / 10; bcol = l % 10;
    Ah = Xh; Bh = W0h; Bl = W0l; ldb = FIND;
    C = FT; ldc = 1280;
  } else {
    role = 2;
    int l = xcd*32 + (idx - 106);            // 0..255
    brow = l >> 3; bcol = l & 7;
    Ah = Xh; Bh = WLh; Bl = WLl; ldb = 2304;
    C = Z1; ldc = 1024;
  }
  const bool three = (role == 0);
  const int row0 = brow*128, col0 = bcol*128;

  const int c0 = 2*w, c1 = 2*w + 1;
  const int rsub = lane >> 2, piece = lane & 3;
  const size_t ld2a = (size_t)FIND*2, ld2b = ldb*2;
  const size_t a0 = (size_t)(row0 + 16*c0 + rsub)*ld2a + piece*16;
  const size_t a1 = (size_t)(row0 + 16*c1 + rsub)*ld2a + piece*16;
  const size_t b0 = (size_t)(col0 + 16*c0 + rsub)*ld2b + piece*16;
  const size_t b1 = (size_t)(col0 + 16*c1 + rsub)*ld2b + piece*16;
  const char* pA0h = (const char*)Ah + a0;  const char* pA1h = (const char*)Ah + a1;
  const char* pA0l = three ? (const char*)Al + a0 : nullptr;
  const char* pA1l = three ? (const char*)Al + a1 : nullptr;
  const char* pB0h = (const char*)Bh + b0;  const char* pB1h = (const char*)Bh + b1;
  const char* pB0l = (const char*)Bl + b0;  const char* pB1l = (const char*)Bl + b1;
  char* lA0h = (char*)sAh + c0*1024;  char* lA1h = (char*)sAh + c1*1024;
  char* lA0l = (char*)sAl + c0*1024;  char* lA1l = (char*)sAl + c1*1024;
  char* lB0h = (char*)sBh + c0*1024;  char* lB1h = (char*)sBh + c1*1024;
  char* lB0l = (char*)sBl + c0*1024;  char* lB1l = (char*)sBl + c1*1024;

  f32x4 acc[4][4] = {};
  for (int kt = 0; kt < 64; ++kt){
    __syncthreads();
    gld16(pA0h, lA0h); gld16(pA1h, lA1h);
    if (three){
      gld16(pA0l, lA0l); gld16(pA1l, lA1l);
      pA0l += 64; pA1l += 64;
    }
    gld16(pB0h, lB0h); gld16(pB1h, lB1h);
    gld16(pB0l, lB0l); gld16(pB1l, lB1l);
    pA0h += 64; pA1h += 64;
    pB0h += 64; pB1h += 64; pB0l += 64; pB1l += 64;
    __syncthreads();
    bf16x8 fb_h[4], fb_l[4];
    #pragma unroll
    for (int j = 0; j < 4; ++j){
      int bo = (wc*64 + j*16 + l15)*32 + lg*8;
      fb_h[j] = *reinterpret_cast<const bf16x8*>(sBh + bo);
      fb_l[j] = *reinterpret_cast<const bf16x8*>(sBl + bo);
    }
    #pragma unroll
    for (int i = 0; i < 4; ++i){
      int ao = (wr*64 + i*16 + l15)*32 + lg*8;
      bf16x8 fah = *reinterpret_cast<const bf16x8*>(sAh + ao);
      #pragma unroll
      for (int j = 0; j < 4; ++j){
        acc[i][j] = __builtin_amdgcn_mfma_f32_16x16x32_bf16(fah, fb_h[j], acc[i][j], 0, 0, 0);
        acc[i][j] = __builtin_amdgcn_mfma_f32_16x16x32_bf16(fah, fb_l[j], acc[i][j], 0, 0, 0);
      }
      if (three){
        bf16x8 fal = *reinterpret_cast<const bf16x8*>(sAl + ao);
        #pragma unroll
        for (int j = 0; j < 4; ++j)
          acc[i][j] = __builtin_amdgcn_mfma_f32_16x16x32_bf16(fal, fb_h[j], acc[i][j], 0, 0, 0);
      }
    }
  }

  if (role == 0){
    #pragma unroll
    for (int i = 0; i < 4; ++i){
      #pragma unroll
      for (int r = 0; r < 4; ++r){
        u64 bits = 0ull;
        #pragma unroll
        for (int j = 0; j < 4; ++j)
          if (acc[i][j][r] > THRESH_) bits |= 1ull << (j*16 + l15);
        #pragma unroll
        for (int m = 1; m <= 8; m <<= 1) bits |= __shfl_xor(bits, m);
        if (l15 == 0){
          int gr = row0 + wr*64 + i*16 + lg*4 + r;
          Mk[(size_t)gr*64 + (col0 >> 6) + wc] = bits;
        }
      }
    }
    if (row0 != col0){
      #pragma unroll
      for (int j = 0; j < 4; ++j){
        u64 tb = 0ull;
        #pragma unroll
        for (int i = 0; i < 4; ++i)
          #pragma unroll
          for (int r = 0; r < 4; ++r)
            if (acc[i][j][r] > THRESH_) tb |= 1ull << (i*16 + lg*4 + r);
        tb |= __shfl_xor(tb, 16);
        tb |= __shfl_xor(tb, 32);
        if (lg == 0){
          int gc = col0 + wc*64 + j*16 + l15;
          Mk[(size_t)gc*64 + (row0 >> 6) + wr] = tb;
        }
      }
    }
  } else {
    const int f32min = (role == 1) ? 1024 : 0;   // role1: fp32 only residual cols
    #pragma unroll
    for (int i = 0; i < 4; ++i){
      int gr = row0 + wr*64 + i*16 + lg*4;
      #pragma unroll
      for (int j = 0; j < 4; ++j){
        int gc = col0 + wc*64 + j*16 + l15;
        #pragma unroll
        for (int r = 0; r < 4; ++r){
          float v = acc[i][j][r];
          if (role == 1 && gc < 1024) FTB[(size_t)(gr + r)*1280 + gc] = f2bf_rne(v);
          if (gc >= f32min) C[(size_t)(gr + r)*ldc + gc] = v;
        }
      }
    }
  }
}

// ---------- 2-term MFMA NT GEMM (A-hi only; B hi+lo) for short-K layers ----------
// EPI: 0 = store (Cb bf16 where gc<bfmax; C fp32 where gc>=f32min); 3 = C += acc,+bias,leaky
template<int EPI>
__global__ void gemm_bf(const unsigned short* __restrict__ Ah,
                        const unsigned short* __restrict__ Bh, const unsigned short* __restrict__ Bl,
                        float* __restrict__ C, unsigned short* __restrict__ Cb,
                        int K, int lda, int ldb, int ldc, int gridx,
                        const float* __restrict__ bias, float param, int f32min, int bfmax){
  __shared__ unsigned short smem[3*128*32];
  unsigned short* sAh = smem;
  unsigned short* sBh = smem + 4096;
  unsigned short* sBl = smem + 8192;
  const int t = threadIdx.x, lane = t & 63, w = t >> 6;
  const int wr = w >> 1, wc = w & 1, l15 = lane & 15, lg = lane >> 4;

  int nwg = gridDim.x, bid = blockIdx.x;
  int wg = ((nwg & 7) == 0) ? ((bid & 7)*(nwg >> 3) + (bid >> 3)) : bid;
  int brow = wg / gridx, bcol = wg % gridx;
  const int row0 = brow*128, col0 = bcol*128;

  const int c0 = 2*w, c1 = 2*w + 1;
  const int rsub = lane >> 2, piece = lane & 3;
  const size_t ld2a = (size_t)lda*2, ld2b = (size_t)ldb*2;
  const size_t a0 = (size_t)(row0 + 16*c0 + rsub)*ld2a + piece*16;
  const size_t a1 = (size_t)(row0 + 16*c1 + rsub)*ld2a + piece*16;
  const size_t b0 = (size_t)(col0 + 16*c0 + rsub)*ld2b + piece*16;
  const size_t b1 = (size_t)(col0 + 16*c1 + rsub)*ld2b + piece*16;
  const char* pA0h = (const char*)Ah + a0;  const char* pA1h = (const char*)Ah + a1;
  const char* pB0h = (const char*)Bh + b0;  const char* pB1h = (const char*)Bh + b1;
  const char* pB0l = (const char*)Bl + b0;  const char* pB1l = (const char*)Bl + b1;
  char* lA0h = (char*)sAh + c0*1024;  char* lA1h = (char*)sAh + c1*1024;
  char* lB0h = (char*)sBh + c0*1024;  char* lB1h = (char*)sBh + c1*1024;
  char* lB0l = (char*)sBl + c0*1024;  char* lB1l = (char*)sBl + c1*1024;

  f32x4 acc[4][4] = {};
  const int nk = K >> 5;
  for (int kt = 0; kt < nk; ++kt){
    __syncthreads();
    gld16(pA0h, lA0h); gld16(pA1h, lA1h);
    gld16(pB0h, lB0h); gld16(pB1h, lB1h);
    gld16(pB0l, lB0l); gld16(pB1l, lB1l);
    pA0h += 64; pA1h += 64;
    pB0h += 64; pB1h += 64; pB0l += 64; pB1l += 64;
    __syncthreads();
    bf16x8 fb_h[4], fb_l[4];
    #pragma unroll
    for (int j = 0; j < 4; ++j){
      int bo = (wc*64 + j*16 + l15)*32 + lg*8;
      fb_h[j] = *reinterpret_cast<const bf16x8*>(sBh + bo);
      fb_l[j] = *reinterpret_cast<const bf16x8*>(sBl + bo);
    }
    #pragma unroll
    for (int i = 0; i < 4; ++i){
      int ao = (wr*64 + i*16 + l15)*32 + lg*8;
      bf16x8 fah = *reinterpret_cast<const bf16x8*>(sAh + ao);
      #pragma unroll
      for (int j = 0; j < 4; ++j){
        acc[i][j] = __builtin_amdgcn_mfma_f32_16x16x32_bf16(fah, fb_h[j], acc[i][j], 0, 0, 0);
        acc[i][j] = __builtin_amdgcn_mfma_f32_16x16x32_bf16(fah, fb_l[j], acc[i][j], 0, 0, 0);
      }
    }
  }

  #pragma unroll
  for (int i = 0; i < 4; ++i){
    int gr = row0 + wr*64 + i*16 + lg*4;
    #pragma unroll
    for (int j = 0; j < 4; ++j){
      int gc = col0 + wc*64 + j*16 + l15;
      #pragma unroll
      for (int r = 0; r < 4; ++r){
        float v = acc[i][j][r];
        size_t o = (size_t)(gr + r)*ldc + gc;
        if (EPI == 3){
          v += C[o] + bias[gc];
          v = v > 0.f ? v : param*v;
          C[o] = v;
        } else {
          if (gc < bfmax) Cb[o] = f2bf_rne(v);
          if (gc >= f32min) C[o] = v;
        }
      }
    }
  }
}

// ---------- single-pass softmax aggregation (bf16 gather, unmasked-max bound) ----------
// NEXTJ: 8 -> emit next-layer el/er (4 heads) via valw; 2 -> 1 head; 0 -> none.
template<int H, bool RELU, bool OUTF32, int NEXTJ>
__global__ void sagg_k(const unsigned short* __restrict__ FTB, int ldf,
                       const u64* __restrict__ Mk,
                       const float* __restrict__ el2, const float* __restrict__ er2,
                       const float* __restrict__ melg,
                       const float* __restrict__ res, int ldres,
                       const float* __restrict__ bias,
                       float* __restrict__ outf,
                       unsigned short* __restrict__ oh,
                       const float* __restrict__ valw,
                       float* __restrict__ el2n, float* __restrict__ er2n){
  int d = blockIdx.x, t = threadIdx.x;
  const int g = t >> 6, q = t & 63;
  const int h = (H == 4) ? g : 0;
  const int wlo = (H == 1) ? g*16 : 0;
  const int whi = (H == 1) ? wlo + 16 : 64;
  const float er2d = er2[(size_t)d*H + h];
  const float sub = er2d + melg[h];
  const float m2 = fmaxf(sub, 0.2f*sub);   // >= all masked scores (leaky monotone)
  const unsigned short* fb = FTB + 4*q + ((H == 4) ? 256*g : 0);
  float4 acc = {0.f, 0.f, 0.f, 0.f};
  float sm = 0.f;
  for (int wdi = wlo; wdi < whi; ++wdi){
    u64 bits = Mk[(size_t)d*64 + wdi];
    while (bits){
      int b = __builtin_ctzll(bits);
      bits &= bits - 1ull;
      int s = wdi*64 + b;
      float sc = er2d + el2[(size_t)s*H + h];
      sc = fmaxf(sc, 0.2f*sc);
      float wt = fexp2(sc - m2);
      sm += wt;
      ushort4 v = *reinterpret_cast<const ushort4*>(fb + (size_t)s*ldf);
      acc.x += wt*bf2f(v.x); acc.y += wt*bf2f(v.y);
      acc.z += wt*bf2f(v.z); acc.w += wt*bf2f(v.w);
    }
  }
  __shared__ float lred[4][256];
  __shared__ float lsm[4];
  if (H == 4){
    float inv = 1.f / sm;    // sm identical across the head's 64 lanes
    acc.x *= inv; acc.y *= inv; acc.z *= inv; acc.w *= inv;
  } else if (q == 0){
    lsm[g] = sm;
  }
  lred[g][q*4+0] = acc.x; lred[g][q*4+1] = acc.y;
  lred[g][q*4+2] = acc.z; lred[g][q*4+3] = acc.w;
  __syncthreads();
  float v = ((lred[0][t] + lred[1][t]) + lred[2][t]) + lred[3][t];
  if (H == 1) v /= (lsm[0] + lsm[1]) + (lsm[2] + lsm[3]);
  v += res[(size_t)d*ldres + t] + bias[t];
  if (RELU) v = fmaxf(v, 0.f);
  if (OUTF32) outf[(size_t)d*HD_ + t] = v;
  oh[(size_t)d*HD_ + t] = f2bf_rne(v);

  // ---- fused next-layer el/er: el_n[d,h] = sum_t v * valw[t][h] (plain stores, no atomics) ----
  if (NEXTJ > 0){
    float p[NEXTJ > 0 ? NEXTJ : 1];
    if (NEXTJ == 8){
      float4 w0 = *reinterpret_cast<const float4*>(valw + (size_t)t*8);
      float4 w1 = *reinterpret_cast<const float4*>(valw + (size_t)t*8 + 4);
      p[0] = v*w0.x; p[1] = v*w0.y; p[2] = v*w0.z; p[3] = v*w0.w;
      p[4] = v*w1.x; p[5] = v*w1.y; p[6] = v*w1.z; p[7] = v*w1.w;
    } else if (NEXTJ == 2){
      float2 w0 = *reinterpret_cast<const float2*>(valw + (size_t)t*2);
      p[0] = v*w0.x; p[1] = v*w0.y;
    }
    __shared__ float ered[4][NEXTJ > 0 ? NEXTJ : 1];
    #pragma unroll
    for (int j = 0; j < NEXTJ; ++j){
      float pv = p[j];
      #pragma unroll
      for (int o = 32; o > 0; o >>= 1) pv += __shfl_down(pv, o);
      if (q == 0) ered[g][j] = pv;
    }
    __syncthreads();
    const int NH = NEXTJ/2;
    if (t < NH){
      int hh = t;
      el2n[(size_t)d*NH + hh] = (ered[0][hh] + ered[1][hh] + ered[2][hh] + ered[3][hh]) * LOG2E_;
      er2n[(size_t)d*NH + hh] = (ered[0][NH+hh] + ered[1][NH+hh] + ered[2][NH+hh] + ered[3][NH+hh]) * LOG2E_;
    }
  }
}

// ---------- classifier head ----------
__global__ void head_k(const float* __restrict__ A, int K, const float* __restrict__ W,
                       const float* __restrict__ b, float* __restrict__ out){
  int row = blockIdx.x, t = threadIdx.x;
  float p[NC_];
  #pragma unroll
  for (int j = 0; j < NC_; ++j) p[j] = 0.f;
  for (int k = t; k < K; k += 256){
    float a = A[(size_t)row*K + k];
    #pragma unroll
    for (int j = 0; j < NC_; ++j) p[j] += a * W[k*NC_ + j];
  }
  #pragma unroll
  for (int j = 0; j < NC_; ++j){
    #pragma unroll
    for (int o = 32; o > 0; o >>= 1) p[j] += __shfl_down(p[j], o);
  }
  __shared__ float red[4][NC_];
  if ((t & 63) == 0){
    #pragma unroll
    for (int j = 0; j < NC_; ++j) red[t >> 6][j] = p[j];
  }
  __syncthreads();
  if (t < NC_)
    out[(size_t)row*NC_ + t] = red[0][t] + red[1][t] + red[2][t] + red[3][t] + b[t];
}

// ---------- launch ----------
extern "C" void kernel_launch(void* const* d_in, const int* in_sizes, int n_in,
                              void* d_out, int out_size, void* d_ws, size_t ws_size,
                              hipStream_t stream){
  const float* x   = (const float*)d_in[0];
  const float* W0  = (const float*)d_in[1];
  const float* al0 = (const float*)d_in[2];
  const float* ar0 = (const float*)d_in[3];
  const float* b0  = (const float*)d_in[4];
  const float* R0  = (const float*)d_in[5];
  const float* W1  = (const float*)d_in[6];
  const float* al1 = (const float*)d_in[7];
  const float* ar1 = (const float*)d_in[8];
  const float* b1  = (const float*)d_in[9];
  const float* R1  = (const float*)d_in[10];
  const float* W2  = (const float*)d_in[11];
  const float* al2 = (const float*)d_in[12];
  const float* ar2 = (const float*)d_in[13];
  const float* b2  = (const float*)d_in[14];
  const float* Wl1 = (const float*)d_in[15];
  const float* bl1 = (const float*)d_in[16];
  const float* Wc1 = (const float*)d_in[17];
  const float* bc1 = (const float*)d_in[18];
  const float* Wc2 = (const float*)d_in[19];
  const float* bc2 = (const float*)d_in[20];
  (void)in_sizes; (void)n_in; (void)out_size; (void)ws_size;

  char* ws = (char*)d_ws;
  size_t off = 0;
  auto alloc = [&](size_t bytes)->char*{
    char* p = ws + off; off += (bytes + 255) & ~(size_t)255; return p;
  };
  typedef unsigned short us;
  u64* MASK = (u64*)alloc((size_t)NNODE*64*8);
  us* W0h = (us*)alloc((size_t)1280*2048*2);  us* W0l = (us*)alloc((size_t)1280*2048*2);
  us* W1h = (us*)alloc((size_t)1280*256*2);   us* W1l = (us*)alloc((size_t)1280*256*2);
  us* W2h = (us*)alloc((size_t)256*256*2);    us* W2l = (us*)alloc((size_t)256*256*2);
  us* WLh = (us*)alloc((size_t)1024*2304*2);  us* WLl = (us*)alloc((size_t)1024*2304*2);
  float* BF0 = (float*)alloc(256*4);
  float* BF1 = (float*)alloc(256*4);
  float* VAL0 = (float*)alloc((size_t)2048*8*4);
  float* VALW1 = (float*)alloc((size_t)256*8*4);
  float* VALW2 = (float*)alloc((size_t)256*2*4);
  float* EL0 = (float*)alloc((size_t)NNODE*4*4);
  float* ER0 = (float*)alloc((size_t)NNODE*4*4);
  float* EL1 = (float*)alloc((size_t)NNODE*4*4);
  float* ER1 = (float*)alloc((size_t)NNODE*4*4);
  float* EL2c = (float*)alloc((size_t)NNODE*4);
  float* ER2c = (float*)alloc((size_t)NNODE*4);
  float* MELG = (float*)alloc(12*4);   // [0..3]=L0, [4..7]=L1, [8]=L2
  us* XNh = (us*)alloc((size_t)NNODE*FIND*2);
  us* XNl = (us*)alloc((size_t)NNODE*FIND*2);
  us* Xh  = (us*)alloc((size_t)NNODE*FIND*2);
  float* FT = (float*)alloc((size_t)NNODE*1280*4);   // fp32 residual cols (1024..1279)
  us* FTB = (us*)alloc((size_t)NNODE*1280*2);        // bf16 feature copy
  float* H2 = (float*)alloc((size_t)NNODE*HD_*4);    // fp32: layer-2 identity residual
  us* H1h = (us*)alloc((size_t)NNODE*HD_*2);
  us* H2h = (us*)alloc((size_t)NNODE*HD_*2);
  us* H3h = (us*)alloc((size_t)NNODE*HD_*2);
  float* Z1 = (float*)alloc((size_t)NNODE*1024*4);

  float* out1 = (float*)d_out;
  float* out2 = out1 + (size_t)NNODE*NC_;

  // ---- weight & input prep ----
  foldT_k<1><<<512, 256, 0, stream>>>(W0, W0h, W0l, 2048, 1024, 32);
  foldT_k<4><<<128, 256, 0, stream>>>(R0, W0h + (size_t)1024*2048, W0l + (size_t)1024*2048, 2048, 256, 32);
  foldT_k<1><<< 64, 256, 0, stream>>>(W1, W1h, W1l, 256, 1024, 4);
  foldT_k<4><<< 16, 256, 0, stream>>>(R1, W1h + (size_t)1024*256, W1l + (size_t)1024*256, 256, 256, 4);
  foldT_k<1><<< 16, 256, 0, stream>>>(W2, W2h, W2l, 256, 256, 4);
  foldT_k<1><<<576, 256, 0, stream>>>(Wl1, WLh, WLl, 2304, 1024, 36);
  bfold_k<<<1, 256, 0, stream>>>(b0, BF0, 4, 256);
  bfold_k<<<1, 256, 0, stream>>>(b1, BF1, 4, 256);
  valprep_k<4><<<2048, 256, 0, stream>>>(W0, al0, ar0, VAL0);
  valprep_k<4><<< 256, 256, 0, stream>>>(W1, al1, ar1, VALW1);
  valprep_k<1><<<  64, 256, 0, stream>>>(W2, al2, ar2, VALW2);
  xprep_k<<<NNODE, 256, 0, stream>>>(x, VAL0, Xh, XNh, XNl, EL0, ER0);
  elmax_k<4><<<4, 256, 0, stream>>>(EL0, MELG);

  // ---- MEGA: per-XCD role mix 66 Gram + 40 GAT0 + 32 MLP ----
  mega_gemm<<<1104, 256, 0, stream>>>(XNh, XNl, Xh, W0h, W0l, WLh, WLl, FT, FTB, Z1, MASK);

  // ---- GAT layer 0 (emits el/er for layer 1) ----
  sagg_k<4,true,false,8><<<NNODE, 256, 0, stream>>>(FTB, 1280, MASK, EL0, ER0, MELG,
      FT + 1024, 1280, BF0, nullptr, H1h, VALW1, EL1, ER1);
  elmax_k<4><<<4, 256, 0, stream>>>(EL1, MELG + 4);

  // ---- GAT layer 1 (emits el/er for layer 2) ----
  gemm_bf<0><<<320, 256, 0, stream>>>(H1h, W1h, W1l, FT, FTB,
      256, 256, 256, 1280, 10, nullptr, 0.f, 1024, 1024);
  sagg_k<4,true,true,2><<<NNODE, 256, 0, stream>>>(FTB, 1280, MASK, EL1, ER1, MELG + 4,
      FT + 1024, 1280, BF1, H2, H2h, VALW2, EL2c, ER2c);
  elmax_k<1><<<1, 256, 0, stream>>>(EL2c, MELG + 8);

  // ---- GAT layer 2 (1 head, identity residual, no relu) ----
  gemm_bf<0><<<64, 256, 0, stream>>>(H2h, W2h, W2l, FT, FTB,
      256, 256, 256, 256, 2, nullptr, 0.f, 1 << 30, 1 << 30);
  sagg_k<1,false,false,0><<<NNODE, 256, 0, stream>>>(FTB, 256, MASK, EL2c, ER2c, MELG + 8,
      H2, 256, b2, nullptr, H3h, nullptr, nullptr, nullptr);

  // ---- MLP: Z1 += h3-part, +bias, leaky ----
  gemm_bf<3><<<256, 256, 0, stream>>>(H3h, WLh + 2048, WLl + 2048, Z1, nullptr,
      256, 256, 2304, 1024, 8, bl1, 0.01f, 0, 0);

  head_k<<<NNODE, 256, 0, stream>>>(Z1, 1024, Wc1, bc1, out1);
  head_k<<<NNODE, 256, 0, stream>>>(x, FIND, Wc2, bc2, out2);
}